// Round 12
// baseline (804.104 us; speedup 1.0000x reference)
//
#include <hip/hip_runtime.h>
#include <cstdint>
#include <type_traits>

typedef uint16_t u16;
typedef uint32_t u32;
typedef __attribute__((ext_vector_type(4))) float f32x4;
typedef __attribute__((ext_vector_type(8))) __bf16 vbf8;
typedef __attribute__((ext_vector_type(8))) short vs8;

// ---- MFMA operand-type hedge: prefer v8bf16, fall back to v8i16 ----
template <typename T, typename = void>
struct CanMfma : std::false_type {};
template <typename T>
struct CanMfma<T, std::void_t<decltype(__builtin_amdgcn_mfma_f32_16x16x32_bf16(
    std::declval<T>(), std::declval<T>(), std::declval<f32x4>(), 0, 0, 0))>>
    : std::true_type {};
typedef std::conditional_t<CanMfma<vbf8>::value, vbf8, vs8> frag_t;

__device__ __forceinline__ f32x4 mfma_bf16(frag_t a, frag_t b, f32x4 c) {
  return __builtin_amdgcn_mfma_f32_16x16x32_bf16(a, b, c, 0, 0, 0);
}

__device__ __forceinline__ u16 f2bf(float f) {
  u32 u = __builtin_bit_cast(u32, f);
  u32 r = (u + 0x7FFFu + ((u >> 16) & 1u)) >> 16;
  return (u16)r;
}

__device__ __forceinline__ void gload_lds16(const void* g, void* l) {
  __builtin_amdgcn_global_load_lds(
      (const __attribute__((address_space(1))) void*)g,
      (__attribute__((address_space(3))) void*)l, 16, 0, 0);
}

// ---------------- cast fp32 -> bf16 ----------------
__global__ __launch_bounds__(256) void cast_f32_bf16(
    const float* __restrict__ in, u16* __restrict__ out, int n8) {
  int i = blockIdx.x * 256 + threadIdx.x;
  const int stride = gridDim.x * 256;
  for (; i < n8; i += stride) {
    const float4 a  = ((const float4*)in)[(size_t)i * 2];
    const float4 b2 = ((const float4*)in)[(size_t)i * 2 + 1];
    uint4 o;
    o.x = (u32)f2bf(a.x)  | ((u32)f2bf(a.y)  << 16);
    o.y = (u32)f2bf(a.z)  | ((u32)f2bf(a.w)  << 16);
    o.z = (u32)f2bf(b2.x) | ((u32)f2bf(b2.y) << 16);
    o.w = (u32)f2bf(b2.z) | ((u32)f2bf(b2.w) << 16);
    ((uint4*)out)[(size_t)i] = o;
  }
}

// ---------------- transpose + cast: in[K][N] f32 -> out[N][K] bf16 ----------------
__global__ __launch_bounds__(256) void transpose_cast(
    const float* __restrict__ in, u16* __restrict__ out, int K, int N) {
  __shared__ float tile[32][33];
  const int k0 = blockIdx.x * 32, n0 = blockIdx.y * 32;
  const int tr = threadIdx.x >> 5, tc = threadIdx.x & 31;
#pragma unroll
  for (int i = 0; i < 4; ++i)
    tile[tr + i * 8][tc] = in[(size_t)(k0 + tr + i * 8) * N + (n0 + tc)];
  __syncthreads();
#pragma unroll
  for (int i = 0; i < 4; ++i)
    out[(size_t)(n0 + tr + i * 8) * K + (k0 + tc)] = f2bf(tile[tc][tr + i * 8]);
}

// ---------------- small GEMM (128^2, 2-phase dbuf) for K/V projections ----------------
template <bool OUT_BF16>
__global__ __launch_bounds__(256) void gemm_bt(
    const u16* __restrict__ A, const u16* __restrict__ Bt,
    const float* __restrict__ bias, void* __restrict__ Cout,
    int M, int N, int K, int Mtiles, int Ntiles) {
  __shared__ char Al[2][128 * 32 * 2];
  __shared__ char Bl[2][128 * 32 * 2];

  const int nwg = Mtiles * Ntiles;
  int bid = (int)blockIdx.x;
  bid = (bid & 7) * (nwg >> 3) + (bid >> 3);
  const int mt = bid / Ntiles, nt = bid % Ntiles;
  const int m0 = mt * 128, n0 = nt * 128;

  const int tid = (int)threadIdx.x;
  const int lane = tid & 63;
  const int wv = tid >> 6;
  const int wm = wv & 1, wn = wv >> 1;
  const int lr = lane & 15, lg = lane >> 4;
  const int rsub = lane >> 2;
  const int slot = lane & 3;
  const int rb0 = n0 + rsub;

  auto stage = [&](int buf, int t) {
    const int k0 = t << 5;
#pragma unroll
    for (int c = 0; c < 2; ++c) {
      const int ci = c * 4 + wv;
      int rra = m0 + ci * 16 + rsub;
      if (rra >= M) rra = M - 1;
      gload_lds16(A + (size_t)rra * K + k0 + slot * 8, Al[buf] + ci * 1024);
      const int rrb = rb0 + ci * 16;
      gload_lds16(Bt + (size_t)rrb * K + k0 + slot * 8, Bl[buf] + ci * 1024);
    }
  };

  f32x4 zero4 = {0.f, 0.f, 0.f, 0.f};
  f32x4 acc[4][4];
#pragma unroll
  for (int i = 0; i < 4; ++i)
#pragma unroll
    for (int j = 0; j < 4; ++j) acc[i][j] = zero4;

  const int nk = K >> 5;
  int cur = 0;
  stage(0, 0);
  __syncthreads();

  for (int t = 0; t < nk; ++t) {
    if (t + 1 < nk) stage(cur ^ 1, t + 1);
    frag_t af[4], bf[4];
#pragma unroll
    for (int i = 0; i < 4; ++i) {
      af[i] = *(const frag_t*)(Al[cur] + (wm * 64 + i * 16 + lr) * 64 + lg * 16);
      bf[i] = *(const frag_t*)(Bl[cur] + (wn * 64 + i * 16 + lr) * 64 + lg * 16);
    }
#pragma unroll
    for (int i = 0; i < 4; ++i)
#pragma unroll
      for (int j = 0; j < 4; ++j)
        acc[i][j] = mfma_bf16(af[i], bf[j], acc[i][j]);
    __syncthreads();
    cur ^= 1;
  }

#pragma unroll
  for (int j = 0; j < 4; ++j) {
    const int col = n0 + wn * 64 + j * 16 + lr;
    const float bv = bias[col];
#pragma unroll
    for (int i = 0; i < 4; ++i) {
      const int rbase = m0 + wm * 64 + i * 16 + lg * 4;
#pragma unroll
      for (int r = 0; r < 4; ++r) {
        const int row = rbase + r;
        const float val = acc[i][j][r] + bv;
        if constexpr (OUT_BF16) {
          u32 me = f2bf(val);
          u32 other = __shfl_xor(me, 1);
          if ((lane & 1) == 0 && row < M) {
            *(u32*)((u16*)Cout + (size_t)row * N + col) = me | (other << 16);
          }
        } else {
          if (row < M) ((float*)Cout)[(size_t)row * N + col] = val;
        }
      }
    }
  }
}

// ---------------- big GEMM: 256x128, BK=64, 3-buffer x 4-phase T3+T4 synthesis -------
// Per K-tile t (buf t%3), 4 quadrant phases; each phase: {ds_reads | stage 1/3 of
// tile t+2 into buf (t+2)%3 (retired at group t-1, provably safe)} -> barrier ->
// lgkmcnt(0)+sched_barrier -> setprio(1) 8 MFMA setprio(0) -> barrier. vmcnt(6) ONLY
// at phase 3: drains exactly tile t+1's 6 loads (issued a full group ago, lead ~2
// group-times > HBM latency), keeps tile t+2's 6 in flight (never 0 mid-loop, T4).
// Serpentine quadrants: a regs reused P0->P1 and P2->P3; b0 held P0->P3.
// LDS 3x(32+16)KB = 144KB -> 1 block/CU, 2 waves/SIMD. Swizzle: 128B rows, 8 slots,
// phys = logical ^ (row&7); consecutive 8 lanes hit 8 distinct slots (conflict-free).
template <bool OUT_BF16>
__global__ __launch_bounds__(512, 2) void gemm_p4(
    const u16* __restrict__ A, const u16* __restrict__ Bt,
    const float* __restrict__ bias, void* __restrict__ Cout,
    int M, int N, int K) {
  __shared__ u16 Al[3][256 * 64];  // 32 KB per K-tile
  __shared__ u16 Bl[3][128 * 64];  // 16 KB per K-tile

  const int Ntiles = N >> 7;
  const int nwg = (M >> 8) * Ntiles;
  int bid = (int)blockIdx.x;
  bid = (bid & 7) * (nwg >> 3) + (bid >> 3);  // bijective: nwg % 8 == 0
  const int mt = bid / Ntiles, ntl = bid % Ntiles;
  const int m0 = mt << 8, n0 = ntl << 7;

  const int tid = (int)threadIdx.x;
  const int lane = tid & 63;
  const int wid = tid >> 6;
  const int wm = wid >> 1, wn = wid & 1;  // 4M x 2N wave grid, wave tile 64x64
  const int lr = lane & 15, lg = lane >> 4;

  // staging: 128B rows (BK=64). Per gload: 8 rows x 128B, src slot pre-swizzled
  // (rule 21): sslot = (lane&7) ^ (lane>>3)  == slot ^ (row&7).
  const int sslot = (lane & 7) ^ (lane >> 3);
  const u16* Ab = A + (size_t)(m0 + wid * 16 + (lane >> 3)) * K + sslot * 8;
  const u16* Bb = Bt + (size_t)(n0 + wid * 16 + (lane >> 3)) * K + sslot * 8;
  const int ldsWOff = wid * 16 * 64;  // wave's 16-row slice base (u16 units)

  auto stageAH = [&](int buf, int H, int t) {  // A half H (128 rows): 2 gloads
    const u16* g = Ab + (size_t)H * 128 * K + t * 64;
    u16* l = &Al[buf][H * 8192 + ldsWOff];
    gload_lds16(g, l);
    gload_lds16(g + (size_t)8 * K, l + 512);
  };
  auto stageB = [&](int buf, int t) {  // B (128 rows): 2 gloads
    const u16* g = Bb + t * 64;
    u16* l = &Bl[buf][ldsWOff];
    gload_lds16(g, l);
    gload_lds16(g + (size_t)8 * K, l + 512);
  };

  // swizzled ds_read of one 16B frag: logical slot = ks*4+lg, phys = logical^(row&7)
  auto ldsF = [&](const u16* base, int row, int ks) -> frag_t {
    const int phys = ((ks << 2) + lg) ^ (row & 7);
    return *(const frag_t*)(base + (size_t)row * 64 + phys * 8);
  };

  f32x4 zero4 = {0.f, 0.f, 0.f, 0.f};
  f32x4 acc[4][4];
#pragma unroll
  for (int i = 0; i < 4; ++i)
#pragma unroll
    for (int j = 0; j < 4; ++j) acc[i][j] = zero4;

  frag_t a[2][2], b0[2][2], b1[2][2];

  auto mmq = [&](frag_t (&bb)[2][2], int ro, int co) {
    __builtin_amdgcn_s_setprio(1);
#pragma unroll
    for (int i = 0; i < 2; ++i)
#pragma unroll
      for (int j = 0; j < 2; ++j) {
        acc[ro + i][co + j] = mfma_bf16(a[i][0], bb[j][0], acc[ro + i][co + j]);
        acc[ro + i][co + j] = mfma_bf16(a[i][1], bb[j][1], acc[ro + i][co + j]);
      }
    __builtin_amdgcn_s_setprio(0);
  };

  const int nt = K >> 6;  // K-tiles (16), >= 3

  // prologue: tiles 0 (buf0) and 1 (buf1); drain tile 0 (vmcnt(6): tile 1 in flight)
  stageAH(0, 0, 0); stageAH(0, 1, 0); stageB(0, 0);
  stageAH(1, 0, 1); stageAH(1, 1, 1); stageB(1, 1);
  asm volatile("s_waitcnt vmcnt(6)" ::: "memory");
  __builtin_amdgcn_s_barrier();

  int c = 0;  // buf = t % 3
  for (int t = 0; t < nt; ++t) {
    const u16* bufA = &Al[c][0];
    const u16* bufB = &Bl[c][0];
    const int c2 = (c + 2 >= 3) ? c - 1 : c + 2;
    const bool st = (t + 2) < nt;
    // ---- P0: read a(rh0), b0(ch0); stage A0(t+2); MFMA q(0,0)
#pragma unroll
    for (int i = 0; i < 2; ++i) {
      a[i][0] = ldsF(bufA, wm * 64 + i * 16 + lr, 0);
      a[i][1] = ldsF(bufA, wm * 64 + i * 16 + lr, 1);
    }
#pragma unroll
    for (int j = 0; j < 2; ++j) {
      b0[j][0] = ldsF(bufB, wn * 64 + j * 16 + lr, 0);
      b0[j][1] = ldsF(bufB, wn * 64 + j * 16 + lr, 1);
    }
    if (st) stageAH(c2, 0, t + 2);
    __builtin_amdgcn_sched_barrier(0);
    __builtin_amdgcn_s_barrier();
    asm volatile("s_waitcnt lgkmcnt(0)" ::: "memory");
    __builtin_amdgcn_sched_barrier(0);
    mmq(b0, 0, 0);
    __builtin_amdgcn_s_barrier();
    // ---- P1: read b1(ch1); stage A1(t+2); MFMA q(0,1)
#pragma unroll
    for (int j = 0; j < 2; ++j) {
      b1[j][0] = ldsF(bufB, wn * 64 + 32 + j * 16 + lr, 0);
      b1[j][1] = ldsF(bufB, wn * 64 + 32 + j * 16 + lr, 1);
    }
    if (st) stageAH(c2, 1, t + 2);
    __builtin_amdgcn_sched_barrier(0);
    __builtin_amdgcn_s_barrier();
    asm volatile("s_waitcnt lgkmcnt(0)" ::: "memory");
    __builtin_amdgcn_sched_barrier(0);
    mmq(b1, 0, 2);
    __builtin_amdgcn_s_barrier();
    // ---- P2: read a(rh1); stage B(t+2); MFMA q(1,1)
#pragma unroll
    for (int i = 0; i < 2; ++i) {
      a[i][0] = ldsF(bufA, wm * 64 + 32 + i * 16 + lr, 0);
      a[i][1] = ldsF(bufA, wm * 64 + 32 + i * 16 + lr, 1);
    }
    if (st) stageB(c2, t + 2);
    __builtin_amdgcn_sched_barrier(0);
    __builtin_amdgcn_s_barrier();
    asm volatile("s_waitcnt lgkmcnt(0)" ::: "memory");
    __builtin_amdgcn_sched_barrier(0);
    mmq(b1, 2, 2);
    __builtin_amdgcn_s_barrier();
    // ---- P3: MFMA q(1,0); counted drain publishes tile t+1 (T4: never 0 mid-loop)
    mmq(b0, 2, 0);
    if (st)
      asm volatile("s_waitcnt vmcnt(6)" ::: "memory");
    else if (t + 2 == nt)
      asm volatile("s_waitcnt vmcnt(0)" ::: "memory");
    if (t + 1 < nt) __builtin_amdgcn_s_barrier();
    c = (c + 1 >= 3) ? 0 : c + 1;
  }

  // epilogue: row = m0+wm*64+ai*16+lg*4+rr ; col = n0+wn*64+bj*16+lr
  float bvv[4];
#pragma unroll
  for (int bj = 0; bj < 4; ++bj) bvv[bj] = bias[n0 + wn * 64 + bj * 16 + lr];
#pragma unroll
  for (int ai = 0; ai < 4; ++ai) {
    const int rbase = m0 + wm * 64 + ai * 16 + lg * 4;
#pragma unroll
    for (int rr = 0; rr < 4; ++rr) {
      const int row = rbase + rr;
#pragma unroll
      for (int bj = 0; bj < 4; ++bj) {
        const int cb = n0 + wn * 64 + bj * 16;
        const float val = acc[ai][bj][rr] + bvv[bj];
        if constexpr (OUT_BF16) {
          u32 me = f2bf(val);
          u32 d0 = me | (__shfl_xor(me, 1) << 16);
          u32 d1 = __shfl_xor(d0, 2);
          if ((lane & 3) == 0) {
            uint2 o; o.x = d0; o.y = d1;
            *(uint2*)((u16*)Cout + (size_t)row * N + cb + (lr & 12)) = o;
          }
        } else {
          float v0 = val;
          float v1 = __shfl_xor(v0, 1);
          float v2 = __shfl_xor(v0, 2);
          float v3 = __shfl_xor(v1, 2);
          if ((lane & 3) == 0) {
            float4 o; o.x = v0; o.y = v1; o.z = v2; o.w = v3;
            *(float4*)((float*)Cout + (size_t)row * N + cb + (lr & 12)) = o;
          }
        }
      }
    }
  }
}

// ---------------- attention (unchanged, passing) ----------------
__global__ __launch_bounds__(256) void attn_kernel(
    const u16* __restrict__ Q, const u16* __restrict__ K,
    const u16* __restrict__ V, u16* __restrict__ O) {
  __shared__ u16 Kl[96][72];
  __shared__ u16 Vt[64][104];

  const int bid = blockIdx.x;
  const int qt = bid & 63;
  const int h = (bid >> 6) & 15;
  const int b = bid >> 10;
  const int tid = threadIdx.x;

#pragma unroll
  for (int it = 0; it < 3; ++it) {
    const int idx = tid + it * 256;
    const int key = idx >> 3, s = idx & 7;
    uint4 val{0u, 0u, 0u, 0u};
    if (key < 77)
      val = *(const uint4*)(K + ((size_t)(b * 77 + key)) * 1024 + h * 64 + s * 8);
    *(uint4*)(&Kl[key][s * 8]) = val;
  }
#pragma unroll
  for (int it = 0; it < 3; ++it) {
    const int idx = tid + it * 256;
    if (idx < 616) {
      const int key = idx >> 3, s = idx & 7;
      const uint4 v4 =
          *(const uint4*)(V + ((size_t)(b * 77 + key)) * 1024 + h * 64 + s * 8);
      const u16* e = (const u16*)&v4;
#pragma unroll
      for (int j = 0; j < 8; ++j) Vt[s * 8 + j][key] = e[j];
    }
  }
#pragma unroll
  for (int it = 0; it < 5; ++it) {
    const int idx = tid + it * 256;
    if (idx < 1216) {
      const int d = idx / 19, kk = 77 + idx % 19;
      Vt[d][kk] = 0;
    }
  }
  __syncthreads();

  const int lane = tid & 63;
  const int wv = tid >> 6;
  const int lr = lane & 15;
  const int lg = lane >> 4;

  const size_t qrow = (size_t)(b * 4096 + qt * 64 + wv * 16 + lr) * 1024 + h * 64;
  frag_t qf[2];
#pragma unroll
  for (int ks = 0; ks < 2; ++ks)
    qf[ks] = *(const frag_t*)(Q + qrow + ks * 32 + lg * 8);

  f32x4 zero4 = {0.f, 0.f, 0.f, 0.f};
  f32x4 sa[5] = {zero4, zero4, zero4, zero4, zero4};
#pragma unroll
  for (int ks = 0; ks < 2; ++ks) {
#pragma unroll
    for (int kt = 0; kt < 5; ++kt) {
      frag_t kf = *(const frag_t*)(&Kl[kt * 16 + lr][ks * 32 + lg * 8]);
      sa[kt] = mfma_bf16(kf, qf[ks], sa[kt]);
    }
  }

  float p[5][4];
  float mx = -3.0e38f;
#pragma unroll
  for (int kt = 0; kt < 5; ++kt)
#pragma unroll
    for (int r = 0; r < 4; ++r) {
      const int key = kt * 16 + lg * 4 + r;
      float s = sa[kt][r] * 0.125f;
      if (key >= 77) s = -3.0e38f;
      p[kt][r] = s;
      mx = fmaxf(mx, s);
    }
  mx = fmaxf(mx, __shfl_xor(mx, 16));
  mx = fmaxf(mx, __shfl_xor(mx, 32));
  float sum = 0.f;
#pragma unroll
  for (int kt = 0; kt < 5; ++kt)
#pragma unroll
    for (int r = 0; r < 4; ++r) {
      const float e = __expf(p[kt][r] - mx);
      p[kt][r] = e;
      sum += e;
    }
  sum += __shfl_xor(sum, 16);
  sum += __shfl_xor(sum, 32);
  const float rden = 1.0f / sum;
#pragma unroll
  for (int kt = 0; kt < 5; ++kt)
#pragma unroll
    for (int r = 0; r < 4; ++r) p[kt][r] *= rden;

  union FP { frag_t v; u16 e[8]; };
  frag_t pa[3];
#pragma unroll
  for (int kb = 0; kb < 3; ++kb) {
    FP f;
#pragma unroll
    for (int j = 0; j < 8; ++j) {
      const int kt = 2 * kb + (j >> 2);
      f.e[j] = (kt < 5) ? f2bf(p[kt][j & 3]) : (u16)0;
    }
    pa[kb] = f.v;
  }

  f32x4 oa[4] = {zero4, zero4, zero4, zero4};
#pragma unroll
  for (int nt = 0; nt < 4; ++nt) {
    const int d = nt * 16 + lr;
#pragma unroll
    for (int kb = 0; kb < 3; ++kb) {
      const int key0 = kb * 32 + lg * 4;
      FP vb;
      *(uint2*)(&vb.e[0]) = *(const uint2*)(&Vt[d][key0]);
      *(uint2*)(&vb.e[4]) = *(const uint2*)(&Vt[d][key0 + 16]);
      oa[nt] = mfma_bf16(pa[kb], vb.v, oa[nt]);
    }
  }

#pragma unroll
  for (int nt = 0; nt < 4; ++nt)
#pragma unroll
    for (int r = 0; r < 4; ++r) {
      const int qr = wv * 16 + lg * 4 + r;
      u32 me = f2bf(oa[nt][r]);
      u32 other = __shfl_xor(me, 1);
      if ((lane & 1) == 0) {
        *(u32*)(O + ((size_t)(b * 4096 + qt * 64 + qr)) * 1024 + h * 64 +
                nt * 16 + lr) = me | (other << 16);
      }
    }
}

// ---------------- launch ----------------
extern "C" void kernel_launch(void* const* d_in, const int* in_sizes, int n_in,
                              void* d_out, int out_size, void* d_ws, size_t ws_size,
                              hipStream_t stream) {
  const float* x  = (const float*)d_in[0];
  const float* p  = (const float*)d_in[1];
  const float* Wq = (const float*)d_in[2];
  const float* bq = (const float*)d_in[3];
  const float* Wk = (const float*)d_in[4];
  const float* bk = (const float*)d_in[5];
  const float* Wv = (const float*)d_in[6];
  const float* bv = (const float*)d_in[7];
  const float* Ww = (const float*)d_in[8];
  const float* bw = (const float*)d_in[9];

  char* ws = (char*)d_ws;
  if (ws_size < 281034752ULL) return;

  u16* x_bf = (u16*)(ws + 0);          // 65536x1024 bf16; reused as attn_out
  u16* q_bf = (u16*)(ws + 134217728);  // 65536x1024
  u16* wq_t = (u16*)(ws + 268435456);  // [1024][1024]
  u16* ww_t = (u16*)(ws + 270532608);  // [1024][1024]
  u16* wk_t = (u16*)(ws + 272629760);  // [1024][512]
  u16* wv_t = (u16*)(ws + 273678336);  // [1024][512]
  u16* p_bf = (u16*)(ws + 274726912);  // 1232x512
  u16* k_bf = (u16*)(ws + 275988480);  // 1232x1024
  u16* v_bf = (u16*)(ws + 278511616);  // 1232x1024

  cast_f32_bf16<<<4096, 256, 0, stream>>>(x, x_bf, 8388608);
  cast_f32_bf16<<<308, 256, 0, stream>>>(p, p_bf, 78848);
  transpose_cast<<<dim3(32, 32), 256, 0, stream>>>(Wq, wq_t, 1024, 1024);
  transpose_cast<<<dim3(32, 32), 256, 0, stream>>>(Ww, ww_t, 1024, 1024);
  transpose_cast<<<dim3(16, 32), 256, 0, stream>>>(Wk, wk_t, 512, 1024);
  transpose_cast<<<dim3(16, 32), 256, 0, stream>>>(Wv, wv_t, 512, 1024);

  // K/V projections (small): 2-phase 128^2 kernel
  gemm_bt<true><<<80, 256, 0, stream>>>(p_bf, wk_t, bk, k_bf, 1232, 1024, 512, 10, 8);
  gemm_bt<true><<<80, 256, 0, stream>>>(p_bf, wv_t, bv, v_bf, 1232, 1024, 512, 10, 8);
  // Q projection: 3-buffer x 4-phase pipeline (2048 blocks)
  gemm_p4<true><<<2048, 512, 0, stream>>>(x_bf, wq_t, bq, q_bf, 65536, 1024, 1024);
  // attention
  attn_kernel<<<16384, 256, 0, stream>>>(q_bf, k_bf, v_bf, x_bf);
  // out projection -> fp32
  gemm_p4<false><<<2048, 512, 0, stream>>>(x_bf, ww_t, bw, d_out, 65536, 1024, 1024);
}

// Round 13
// 615.729 us; speedup vs baseline: 1.3059x; 1.3059x over previous
//
#include <hip/hip_runtime.h>
#include <cstdint>
#include <type_traits>

typedef uint16_t u16;
typedef uint32_t u32;
typedef __attribute__((ext_vector_type(4))) float f32x4;
typedef __attribute__((ext_vector_type(8))) __bf16 vbf8;
typedef __attribute__((ext_vector_type(8))) short vs8;

// ---- MFMA operand-type hedge: prefer v8bf16, fall back to v8i16 ----
template <typename T, typename = void>
struct CanMfma : std::false_type {};
template <typename T>
struct CanMfma<T, std::void_t<decltype(__builtin_amdgcn_mfma_f32_16x16x32_bf16(
    std::declval<T>(), std::declval<T>(), std::declval<f32x4>(), 0, 0, 0))>>
    : std::true_type {};
typedef std::conditional_t<CanMfma<vbf8>::value, vbf8, vs8> frag_t;

__device__ __forceinline__ f32x4 mfma_bf16(frag_t a, frag_t b, f32x4 c) {
  return __builtin_amdgcn_mfma_f32_16x16x32_bf16(a, b, c, 0, 0, 0);
}

__device__ __forceinline__ u16 f2bf(float f) {
  u32 u = __builtin_bit_cast(u32, f);
  u32 r = (u + 0x7FFFu + ((u >> 16) & 1u)) >> 16;
  return (u16)r;
}

__device__ __forceinline__ void gload_lds16(const void* g, void* l) {
  __builtin_amdgcn_global_load_lds(
      (const __attribute__((address_space(1))) void*)g,
      (__attribute__((address_space(3))) void*)l, 16, 0, 0);
}

// ---------------- cast fp32 -> bf16 ----------------
__global__ __launch_bounds__(256) void cast_f32_bf16(
    const float* __restrict__ in, u16* __restrict__ out, int n8) {
  int i = blockIdx.x * 256 + threadIdx.x;
  const int stride = gridDim.x * 256;
  for (; i < n8; i += stride) {
    const float4 a  = ((const float4*)in)[(size_t)i * 2];
    const float4 b2 = ((const float4*)in)[(size_t)i * 2 + 1];
    uint4 o;
    o.x = (u32)f2bf(a.x)  | ((u32)f2bf(a.y)  << 16);
    o.y = (u32)f2bf(a.z)  | ((u32)f2bf(a.w)  << 16);
    o.z = (u32)f2bf(b2.x) | ((u32)f2bf(b2.y) << 16);
    o.w = (u32)f2bf(b2.z) | ((u32)f2bf(b2.w) << 16);
    ((uint4*)out)[(size_t)i] = o;
  }
}

// ---------------- transpose + cast: in[K][N] f32 -> out[N][K] bf16 ----------------
__global__ __launch_bounds__(256) void transpose_cast(
    const float* __restrict__ in, u16* __restrict__ out, int K, int N) {
  __shared__ float tile[32][33];
  const int k0 = blockIdx.x * 32, n0 = blockIdx.y * 32;
  const int tr = threadIdx.x >> 5, tc = threadIdx.x & 31;
#pragma unroll
  for (int i = 0; i < 4; ++i)
    tile[tr + i * 8][tc] = in[(size_t)(k0 + tr + i * 8) * N + (n0 + tc)];
  __syncthreads();
#pragma unroll
  for (int i = 0; i < 4; ++i)
    out[(size_t)(n0 + tr + i * 8) * K + (k0 + tc)] = f2bf(tile[tc][tr + i * 8]);
}

// ---------------- small GEMM (128^2, 2-phase dbuf) for K/V projections ----------------
template <bool OUT_BF16>
__global__ __launch_bounds__(256) void gemm_bt(
    const u16* __restrict__ A, const u16* __restrict__ Bt,
    const float* __restrict__ bias, void* __restrict__ Cout,
    int M, int N, int K, int Mtiles, int Ntiles) {
  __shared__ char Al[2][128 * 32 * 2];
  __shared__ char Bl[2][128 * 32 * 2];

  const int nwg = Mtiles * Ntiles;
  int bid = (int)blockIdx.x;
  bid = (bid & 7) * (nwg >> 3) + (bid >> 3);
  const int mt = bid / Ntiles, nt = bid % Ntiles;
  const int m0 = mt * 128, n0 = nt * 128;

  const int tid = (int)threadIdx.x;
  const int lane = tid & 63;
  const int wv = tid >> 6;
  const int wm = wv & 1, wn = wv >> 1;
  const int lr = lane & 15, lg = lane >> 4;
  const int rsub = lane >> 2;
  const int slot = lane & 3;
  const int rb0 = n0 + rsub;

  auto stage = [&](int buf, int t) {
    const int k0 = t << 5;
#pragma unroll
    for (int c = 0; c < 2; ++c) {
      const int ci = c * 4 + wv;
      int rra = m0 + ci * 16 + rsub;
      if (rra >= M) rra = M - 1;
      gload_lds16(A + (size_t)rra * K + k0 + slot * 8, Al[buf] + ci * 1024);
      const int rrb = rb0 + ci * 16;
      gload_lds16(Bt + (size_t)rrb * K + k0 + slot * 8, Bl[buf] + ci * 1024);
    }
  };

  f32x4 zero4 = {0.f, 0.f, 0.f, 0.f};
  f32x4 acc[4][4];
#pragma unroll
  for (int i = 0; i < 4; ++i)
#pragma unroll
    for (int j = 0; j < 4; ++j) acc[i][j] = zero4;

  const int nk = K >> 5;
  int cur = 0;
  stage(0, 0);
  __syncthreads();

  for (int t = 0; t < nk; ++t) {
    if (t + 1 < nk) stage(cur ^ 1, t + 1);
    frag_t af[4], bf[4];
#pragma unroll
    for (int i = 0; i < 4; ++i) {
      af[i] = *(const frag_t*)(Al[cur] + (wm * 64 + i * 16 + lr) * 64 + lg * 16);
      bf[i] = *(const frag_t*)(Bl[cur] + (wn * 64 + i * 16 + lr) * 64 + lg * 16);
    }
#pragma unroll
    for (int i = 0; i < 4; ++i)
#pragma unroll
      for (int j = 0; j < 4; ++j)
        acc[i][j] = mfma_bf16(af[i], bf[j], acc[i][j]);
    __syncthreads();
    cur ^= 1;
  }

#pragma unroll
  for (int j = 0; j < 4; ++j) {
    const int col = n0 + wn * 64 + j * 16 + lr;
    const float bv = bias[col];
#pragma unroll
    for (int i = 0; i < 4; ++i) {
      const int rbase = m0 + wm * 64 + i * 16 + lg * 4;
#pragma unroll
      for (int r = 0; r < 4; ++r) {
        const int row = rbase + r;
        const float val = acc[i][j][r] + bv;
        if constexpr (OUT_BF16) {
          u32 me = f2bf(val);
          u32 other = __shfl_xor(me, 1);
          if ((lane & 1) == 0 && row < M) {
            *(u32*)((u16*)Cout + (size_t)row * N + col) = me | (other << 16);
          }
        } else {
          if (row < M) ((float*)Cout)[(size_t)row * N + col] = val;
        }
      }
    }
  }
}

// ---------------- big GEMM: 256x128 tile, BK=32, 2-phase, 2 blocks/CU ----------------
// Best-measured clean structure (R7/Round-8: 233-237us, MfmaUtil ~24%, conflicts 0,
// occupancy ~41%). ONE vmcnt(0)+barrier per K-tile; single scheduling region.
template <bool OUT_BF16>
__global__ __launch_bounds__(512, 4) void gemm256(
    const u16* __restrict__ A, const u16* __restrict__ Bt,
    const float* __restrict__ bias, void* __restrict__ Cout,
    int M, int N, int K) {
  __shared__ u16 Al[2][256 * 32];  // 16 KB per buffer
  __shared__ u16 Bl[2][128 * 32];  //  8 KB per buffer

  const int Ntiles = N >> 7;
  const int nwg = (M >> 8) * Ntiles;
  int bid = (int)blockIdx.x;
  bid = (bid & 7) * (nwg >> 3) + (bid >> 3);  // bijective: nwg % 8 == 0
  const int mt = bid / Ntiles, ntl = bid % Ntiles;
  const int m0 = mt << 8, n0 = ntl << 7;

  const int tid = (int)threadIdx.x;
  const int lane = tid & 63;
  const int wid = tid >> 6;
  const int wm = wid >> 1, wn = wid & 1;  // 4 x 2 wave grid, per-wave 64x64
  const int lr = lane & 15, lg = lane >> 4;

  // staging: rows of 64B (BK=32); source slot pre-swizzled (rule 21):
  // sslot = (lane&3) ^ ((lane>>3)&3) == slot ^ ((row>>1)&3).
  const int srow = lane >> 2;
  const int sslot = (lane & 3) ^ ((lane >> 3) & 3);
  const u16* Abase = A + (size_t)(m0 + wid * 32 + srow) * K + sslot * 8;
  const u16* Bbase = Bt + (size_t)(n0 + wid * 16 + srow) * K + sslot * 8;

  auto stage = [&](u16* da, u16* db, int t) {
    const int k0 = t << 5;
    gload_lds16(Abase + k0, (char*)da + wid * 2048);
    gload_lds16(Abase + ((size_t)K << 4) + k0, (char*)da + wid * 2048 + 1024);
    gload_lds16(Bbase + k0, (char*)db + wid * 1024);
  };

  // swizzled ds_read of one 16B frag: logical slot = lg, phys = lg ^ ((row>>1)&3)
  auto ldsF = [&](const u16* base, int row) -> frag_t {
    const int phys = lg ^ ((row >> 1) & 3);
    return *(const frag_t*)(base + (size_t)row * 32 + phys * 8);
  };

  f32x4 zero4 = {0.f, 0.f, 0.f, 0.f};
  f32x4 acc[4][4];
#pragma unroll
  for (int i = 0; i < 4; ++i)
#pragma unroll
    for (int j = 0; j < 4; ++j) acc[i][j] = zero4;

  const int nt = K >> 5;  // K-tiles, >= 2
  const int ar0 = wm * 64 + lr;
  const int br0 = wn * 64 + lr;

  // prologue: stage tiles 0 and 1; wait tile 0 only (vmcnt(3): tile 1 in flight)
  stage(&Al[0][0], &Bl[0][0], 0);
  stage(&Al[1][0], &Bl[1][0], 1);
  asm volatile("s_waitcnt vmcnt(3)" ::: "memory");
  __builtin_amdgcn_s_barrier();

  for (int t = 0; t < nt; ++t) {
    const int cur = t & 1;
    const u16* al = &Al[cur][0];
    const u16* bl = &Bl[cur][0];
    // stage tile t+1 into the buffer consumed at t-1 (read done, barrier passed)
    if (t >= 1 && t + 1 < nt)
      stage(&Al[cur ^ 1][0], &Bl[cur ^ 1][0], t + 1);
    // single scheduling region: 8 ds_read_b128 + 16 MFMA, compiler interleaves
    frag_t a[4], b[4];
#pragma unroll
    for (int i = 0; i < 4; ++i) a[i] = ldsF(al, ar0 + i * 16);
#pragma unroll
    for (int j = 0; j < 4; ++j) b[j] = ldsF(bl, br0 + j * 16);
#pragma unroll
    for (int i = 0; i < 4; ++i)
#pragma unroll
      for (int j = 0; j < 4; ++j)
        acc[i][j] = mfma_bf16(a[i], b[j], acc[i][j]);
    if (t + 1 < nt) {
      asm volatile("s_waitcnt vmcnt(0)" ::: "memory");
      __builtin_amdgcn_s_barrier();
    }
  }

  // epilogue: row = m0+wm*64+ai*16+lg*4+rr ; col = n0+wn*64+bj*16+lr
  float bvv[4];
#pragma unroll
  for (int bj = 0; bj < 4; ++bj) bvv[bj] = bias[n0 + wn * 64 + bj * 16 + lr];
#pragma unroll
  for (int ai = 0; ai < 4; ++ai) {
    const int rbase = m0 + wm * 64 + ai * 16 + lg * 4;
#pragma unroll
    for (int rr = 0; rr < 4; ++rr) {
      const int row = rbase + rr;
#pragma unroll
      for (int bj = 0; bj < 4; ++bj) {
        const int cb = n0 + wn * 64 + bj * 16;
        const float val = acc[ai][bj][rr] + bvv[bj];
        if constexpr (OUT_BF16) {
          u32 me = f2bf(val);
          u32 d0 = me | (__shfl_xor(me, 1) << 16);
          u32 d1 = __shfl_xor(d0, 2);
          if ((lane & 3) == 0) {
            uint2 o; o.x = d0; o.y = d1;
            *(uint2*)((u16*)Cout + (size_t)row * N + cb + (lr & 12)) = o;
          }
        } else {
          float v0 = val;
          float v1 = __shfl_xor(v0, 1);
          float v2 = __shfl_xor(v0, 2);
          float v3 = __shfl_xor(v1, 2);
          if ((lane & 3) == 0) {
            float4 o; o.x = v0; o.y = v1; o.z = v2; o.w = v3;
            *(float4*)((float*)Cout + (size_t)row * N + cb + (lr & 12)) = o;
          }
        }
      }
    }
  }
}

// ---------------- attention: 4 q-tiles per block (K/V staging amortized 4x) --------
// Per (b,h): K/V staged once per block instead of once per q-tile. Body per q-tile
// unchanged (swapped QK^T, 4-lane-group softmax, in-register P, PV via Vt).
__global__ __launch_bounds__(256) void attn_kernel(
    const u16* __restrict__ Q, const u16* __restrict__ K,
    const u16* __restrict__ V, u16* __restrict__ O) {
  __shared__ u16 Kl[96][72];
  __shared__ u16 Vt[64][104];

  const int bid = blockIdx.x;   // 4096 = 16 qgroups x 16 heads x 16 batch
  const int qt0 = bid & 15;
  const int h = (bid >> 4) & 15;
  const int b = bid >> 8;
  const int tid = threadIdx.x;

#pragma unroll
  for (int it = 0; it < 3; ++it) {
    const int idx = tid + it * 256;
    const int key = idx >> 3, s = idx & 7;
    uint4 val{0u, 0u, 0u, 0u};
    if (key < 77)
      val = *(const uint4*)(K + ((size_t)(b * 77 + key)) * 1024 + h * 64 + s * 8);
    *(uint4*)(&Kl[key][s * 8]) = val;
  }
#pragma unroll
  for (int it = 0; it < 3; ++it) {
    const int idx = tid + it * 256;
    if (idx < 616) {
      const int key = idx >> 3, s = idx & 7;
      const uint4 v4 =
          *(const uint4*)(V + ((size_t)(b * 77 + key)) * 1024 + h * 64 + s * 8);
      const u16* e = (const u16*)&v4;
#pragma unroll
      for (int j = 0; j < 8; ++j) Vt[s * 8 + j][key] = e[j];
    }
  }
#pragma unroll
  for (int it = 0; it < 5; ++it) {
    const int idx = tid + it * 256;
    if (idx < 1216) {
      const int d = idx / 19, kk = 77 + idx % 19;
      Vt[d][kk] = 0;
    }
  }
  __syncthreads();

  const int lane = tid & 63;
  const int wv = tid >> 6;
  const int lr = lane & 15;
  const int lg = lane >> 4;
  f32x4 zero4 = {0.f, 0.f, 0.f, 0.f};

  for (int q4 = 0; q4 < 4; ++q4) {
    const int qt = qt0 * 4 + q4;

    const size_t qrow = (size_t)(b * 4096 + qt * 64 + wv * 16 + lr) * 1024 + h * 64;
    frag_t qf[2];
#pragma unroll
    for (int ks = 0; ks < 2; ++ks)
      qf[ks] = *(const frag_t*)(Q + qrow + ks * 32 + lg * 8);

    f32x4 sa[5] = {zero4, zero4, zero4, zero4, zero4};
#pragma unroll
    for (int ks = 0; ks < 2; ++ks) {
#pragma unroll
      for (int kt = 0; kt < 5; ++kt) {
        frag_t kf = *(const frag_t*)(&Kl[kt * 16 + lr][ks * 32 + lg * 8]);
        sa[kt] = mfma_bf16(kf, qf[ks], sa[kt]);
      }
    }

    float p[5][4];
    float mx = -3.0e38f;
#pragma unroll
    for (int kt = 0; kt < 5; ++kt)
#pragma unroll
      for (int r = 0; r < 4; ++r) {
        const int key = kt * 16 + lg * 4 + r;
        float s = sa[kt][r] * 0.125f;
        if (key >= 77) s = -3.0e38f;
        p[kt][r] = s;
        mx = fmaxf(mx, s);
      }
    mx = fmaxf(mx, __shfl_xor(mx, 16));
    mx = fmaxf(mx, __shfl_xor(mx, 32));
    float sum = 0.f;
#pragma unroll
    for (int kt = 0; kt < 5; ++kt)
#pragma unroll
      for (int r = 0; r < 4; ++r) {
        const float e = __expf(p[kt][r] - mx);
        p[kt][r] = e;
        sum += e;
      }
    sum += __shfl_xor(sum, 16);
    sum += __shfl_xor(sum, 32);
    const float rden = 1.0f / sum;
#pragma unroll
    for (int kt = 0; kt < 5; ++kt)
#pragma unroll
      for (int r = 0; r < 4; ++r) p[kt][r] *= rden;

    union FP { frag_t v; u16 e[8]; };
    frag_t pa[3];
#pragma unroll
    for (int kb = 0; kb < 3; ++kb) {
      FP f;
#pragma unroll
      for (int j = 0; j < 8; ++j) {
        const int kt = 2 * kb + (j >> 2);
        f.e[j] = (kt < 5) ? f2bf(p[kt][j & 3]) : (u16)0;
      }
      pa[kb] = f.v;
    }

    f32x4 oa[4] = {zero4, zero4, zero4, zero4};
#pragma unroll
    for (int nt = 0; nt < 4; ++nt) {
      const int d = nt * 16 + lr;
#pragma unroll
      for (int kb = 0; kb < 3; ++kb) {
        const int key0 = kb * 32 + lg * 4;
        FP vb;
        *(uint2*)(&vb.e[0]) = *(const uint2*)(&Vt[d][key0]);
        *(uint2*)(&vb.e[4]) = *(const uint2*)(&Vt[d][key0 + 16]);
        oa[nt] = mfma_bf16(pa[kb], vb.v, oa[nt]);
      }
    }

#pragma unroll
    for (int nt = 0; nt < 4; ++nt)
#pragma unroll
      for (int r = 0; r < 4; ++r) {
        const int qr = wv * 16 + lg * 4 + r;
        u32 me = f2bf(oa[nt][r]);
        u32 other = __shfl_xor(me, 1);
        if ((lane & 1) == 0) {
          *(u32*)(O + ((size_t)(b * 4096 + qt * 64 + qr)) * 1024 + h * 64 +
                  nt * 16 + lr) = me | (other << 16);
        }
      }
  }
}

// ---------------- launch ----------------
extern "C" void kernel_launch(void* const* d_in, const int* in_sizes, int n_in,
                              void* d_out, int out_size, void* d_ws, size_t ws_size,
                              hipStream_t stream) {
  const float* x  = (const float*)d_in[0];
  const float* p  = (const float*)d_in[1];
  const float* Wq = (const float*)d_in[2];
  const float* bq = (const float*)d_in[3];
  const float* Wk = (const float*)d_in[4];
  const float* bk = (const float*)d_in[5];
  const float* Wv = (const float*)d_in[6];
  const float* bv = (const float*)d_in[7];
  const float* Ww = (const float*)d_in[8];
  const float* bw = (const float*)d_in[9];

  char* ws = (char*)d_ws;
  if (ws_size < 281034752ULL) return;

  u16* x_bf = (u16*)(ws + 0);          // 65536x1024 bf16; reused as attn_out
  u16* q_bf = (u16*)(ws + 134217728);  // 65536x1024
  u16* wq_t = (u16*)(ws + 268435456);  // [1024][1024]
  u16* ww_t = (u16*)(ws + 270532608);  // [1024][1024]
  u16* wk_t = (u16*)(ws + 272629760);  // [1024][512]
  u16* wv_t = (u16*)(ws + 273678336);  // [1024][512]
  u16* p_bf = (u16*)(ws + 274726912);  // 1232x512
  u16* k_bf = (u16*)(ws + 275988480);  // 1232x1024
  u16* v_bf = (u16*)(ws + 278511616);  // 1232x1024

  cast_f32_bf16<<<4096, 256, 0, stream>>>(x, x_bf, 8388608);
  cast_f32_bf16<<<308, 256, 0, stream>>>(p, p_bf, 78848);
  transpose_cast<<<dim3(32, 32), 256, 0, stream>>>(Wq, wq_t, 1024, 1024);
  transpose_cast<<<dim3(32, 32), 256, 0, stream>>>(Ww, ww_t, 1024, 1024);
  transpose_cast<<<dim3(16, 32), 256, 0, stream>>>(Wk, wk_t, 512, 1024);
  transpose_cast<<<dim3(16, 32), 256, 0, stream>>>(Wv, wv_t, 512, 1024);

  // K/V projections (small): 2-phase 128^2 kernel
  gemm_bt<true><<<80, 256, 0, stream>>>(p_bf, wk_t, bk, k_bf, 1232, 1024, 512, 10, 8);
  gemm_bt<true><<<80, 256, 0, stream>>>(p_bf, wv_t, bv, v_bf, 1232, 1024, 512, 10, 8);
  // Q projection: 256x128 tile, 2 blocks/CU (2048 blocks)
  gemm256<true><<<2048, 512, 0, stream>>>(x_bf, wq_t, bq, q_bf, 65536, 1024, 1024);
  // attention: 4 q-tiles per block (4096 blocks)
  attn_kernel<<<4096, 256, 0, stream>>>(q_bf, k_bf, v_bf, x_bf);
  // out projection -> fp32
  gemm256<false><<<2048, 512, 0, stream>>>(x_bf, ww_t, bw, d_out, 65536, 1024, 1024);
}

// Round 14
// 589.306 us; speedup vs baseline: 1.3645x; 1.0448x over previous
//
#include <hip/hip_runtime.h>
#include <cstdint>
#include <type_traits>

typedef uint16_t u16;
typedef uint32_t u32;
typedef __attribute__((ext_vector_type(4))) float f32x4;
typedef __attribute__((ext_vector_type(8))) __bf16 vbf8;
typedef __attribute__((ext_vector_type(8))) short vs8;

// ---- MFMA operand-type hedge: prefer v8bf16, fall back to v8i16 ----
template <typename T, typename = void>
struct CanMfma : std::false_type {};
template <typename T>
struct CanMfma<T, std::void_t<decltype(__builtin_amdgcn_mfma_f32_16x16x32_bf16(
    std::declval<T>(), std::declval<T>(), std::declval<f32x4>(), 0, 0, 0))>>
    : std::true_type {};
typedef std::conditional_t<CanMfma<vbf8>::value, vbf8, vs8> frag_t;

__device__ __forceinline__ f32x4 mfma_bf16(frag_t a, frag_t b, f32x4 c) {
  return __builtin_amdgcn_mfma_f32_16x16x32_bf16(a, b, c, 0, 0, 0);
}

__device__ __forceinline__ u16 f2bf(float f) {
  u32 u = __builtin_bit_cast(u32, f);
  u32 r = (u + 0x7FFFu + ((u >> 16) & 1u)) >> 16;
  return (u16)r;
}

__device__ __forceinline__ void gload_lds16(const void* g, void* l) {
  __builtin_amdgcn_global_load_lds(
      (const __attribute__((address_space(1))) void*)g,
      (__attribute__((address_space(3))) void*)l, 16, 0, 0);
}

// ---------------- merged prep: cast_x + cast_p + 4 weight transposes ----------------
// Block ranges (all 256-thread):
//   [0, 32768)        cast x  (65536x1024 f32 -> bf16), 8 elems/thread, exact
//   [32768, 33076)    cast p  (630784 elems)
//   [33076, 34100)    Wq transpose-cast 1024x1024 -> wq_t[1024][1024]
//   [34100, 35124)    Ww transpose-cast -> ww_t
//   [35124, 35636)    Wk transpose-cast 512x1024 -> wkv_t rows 0..1023
//   [35636, 36148)    Wv transpose-cast -> wkv_t rows 1024..2047
__device__ __forceinline__ void transpose_body(
    const float* __restrict__ in, u16* __restrict__ out, int K, int N,
    int k0, int n0, float (*tile)[33]) {
  const int tr = threadIdx.x >> 5, tc = threadIdx.x & 31;
#pragma unroll
  for (int i = 0; i < 4; ++i)
    tile[tr + i * 8][tc] = in[(size_t)(k0 + tr + i * 8) * N + (n0 + tc)];
  __syncthreads();
#pragma unroll
  for (int i = 0; i < 4; ++i)
    out[(size_t)(n0 + tr + i * 8) * K + (k0 + tc)] = f2bf(tile[tc][tr + i * 8]);
}

__global__ __launch_bounds__(256) void prep_kernel(
    const float* __restrict__ x, const float* __restrict__ p,
    const float* __restrict__ Wq, const float* __restrict__ Ww,
    const float* __restrict__ Wk, const float* __restrict__ Wv,
    u16* __restrict__ x_bf, u16* __restrict__ p_bf,
    u16* __restrict__ wq_t, u16* __restrict__ ww_t, u16* __restrict__ wkv_t) {
  __shared__ float tile[32][33];
  const int bid = blockIdx.x;
  if (bid < 32768) {
    const size_t i = (size_t)bid * 256 + threadIdx.x;  // < 8388608 exactly
    const float4 a  = ((const float4*)x)[i * 2];
    const float4 b2 = ((const float4*)x)[i * 2 + 1];
    uint4 o;
    o.x = (u32)f2bf(a.x)  | ((u32)f2bf(a.y)  << 16);
    o.y = (u32)f2bf(a.z)  | ((u32)f2bf(a.w)  << 16);
    o.z = (u32)f2bf(b2.x) | ((u32)f2bf(b2.y) << 16);
    o.w = (u32)f2bf(b2.z) | ((u32)f2bf(b2.w) << 16);
    ((uint4*)x_bf)[i] = o;
  } else if (bid < 33076) {
    const int i = (bid - 32768) * 256 + threadIdx.x;
    if (i < 78848) {
      const float4 a  = ((const float4*)p)[(size_t)i * 2];
      const float4 b2 = ((const float4*)p)[(size_t)i * 2 + 1];
      uint4 o;
      o.x = (u32)f2bf(a.x)  | ((u32)f2bf(a.y)  << 16);
      o.y = (u32)f2bf(a.z)  | ((u32)f2bf(a.w)  << 16);
      o.z = (u32)f2bf(b2.x) | ((u32)f2bf(b2.y) << 16);
      o.w = (u32)f2bf(b2.z) | ((u32)f2bf(b2.w) << 16);
      ((uint4*)p_bf)[(size_t)i] = o;
    }
  } else if (bid < 35124) {
    const bool isQ = bid < 34100;
    const int r = (bid - (isQ ? 33076 : 34100));  // 0..1023
    transpose_body(isQ ? Wq : Ww, isQ ? wq_t : ww_t, 1024, 1024,
                   (r & 31) * 32, (r >> 5) * 32, tile);
  } else {
    const bool isK = bid < 35636;
    const int r = (bid - (isK ? 35124 : 35636));  // 0..511
    transpose_body(isK ? Wk : Wv, isK ? wkv_t : (wkv_t + 1024 * 512), 512, 1024,
                   (r & 15) * 32, (r >> 4) * 32, tile);
  }
}

// ---------------- small GEMM (128^2, 2-phase dbuf): merged K/V projection ------------
// N may exceed 1024; bias selected per column: col<1024 -> biasA[col], else biasB[col-1024].
template <bool OUT_BF16>
__global__ __launch_bounds__(256) void gemm_bt(
    const u16* __restrict__ A, const u16* __restrict__ Bt,
    const float* __restrict__ biasA, const float* __restrict__ biasB,
    void* __restrict__ Cout,
    int M, int N, int K, int Mtiles, int Ntiles) {
  __shared__ char Al[2][128 * 32 * 2];
  __shared__ char Bl[2][128 * 32 * 2];

  const int nwg = Mtiles * Ntiles;
  int bid = (int)blockIdx.x;
  bid = (bid & 7) * (nwg >> 3) + (bid >> 3);
  const int mt = bid / Ntiles, nt = bid % Ntiles;
  const int m0 = mt * 128, n0 = nt * 128;

  const int tid = (int)threadIdx.x;
  const int lane = tid & 63;
  const int wv = tid >> 6;
  const int wm = wv & 1, wn = wv >> 1;
  const int lr = lane & 15, lg = lane >> 4;
  const int rsub = lane >> 2;
  const int slot = lane & 3;
  const int rb0 = n0 + rsub;

  auto stage = [&](int buf, int t) {
    const int k0 = t << 5;
#pragma unroll
    for (int c = 0; c < 2; ++c) {
      const int ci = c * 4 + wv;
      int rra = m0 + ci * 16 + rsub;
      if (rra >= M) rra = M - 1;
      gload_lds16(A + (size_t)rra * K + k0 + slot * 8, Al[buf] + ci * 1024);
      const int rrb = rb0 + ci * 16;
      gload_lds16(Bt + (size_t)rrb * K + k0 + slot * 8, Bl[buf] + ci * 1024);
    }
  };

  f32x4 zero4 = {0.f, 0.f, 0.f, 0.f};
  f32x4 acc[4][4];
#pragma unroll
  for (int i = 0; i < 4; ++i)
#pragma unroll
    for (int j = 0; j < 4; ++j) acc[i][j] = zero4;

  const int nk = K >> 5;
  int cur = 0;
  stage(0, 0);
  __syncthreads();

  for (int t = 0; t < nk; ++t) {
    if (t + 1 < nk) stage(cur ^ 1, t + 1);
    frag_t af[4], bf[4];
#pragma unroll
    for (int i = 0; i < 4; ++i) {
      af[i] = *(const frag_t*)(Al[cur] + (wm * 64 + i * 16 + lr) * 64 + lg * 16);
      bf[i] = *(const frag_t*)(Bl[cur] + (wn * 64 + i * 16 + lr) * 64 + lg * 16);
    }
#pragma unroll
    for (int i = 0; i < 4; ++i)
#pragma unroll
      for (int j = 0; j < 4; ++j)
        acc[i][j] = mfma_bf16(af[i], bf[j], acc[i][j]);
    __syncthreads();
    cur ^= 1;
  }

#pragma unroll
  for (int j = 0; j < 4; ++j) {
    const int col = n0 + wn * 64 + j * 16 + lr;
    const float bv = (col < 1024) ? biasA[col] : biasB[col - 1024];
#pragma unroll
    for (int i = 0; i < 4; ++i) {
      const int rbase = m0 + wm * 64 + i * 16 + lg * 4;
#pragma unroll
      for (int r = 0; r < 4; ++r) {
        const int row = rbase + r;
        const float val = acc[i][j][r] + bv;
        if constexpr (OUT_BF16) {
          u32 me = f2bf(val);
          u32 other = __shfl_xor(me, 1);
          if ((lane & 1) == 0 && row < M) {
            *(u32*)((u16*)Cout + (size_t)row * N + col) = me | (other << 16);
          }
        } else {
          if (row < M) ((float*)Cout)[(size_t)row * N + col] = val;
        }
      }
    }
  }
}

// ---------------- big GEMM: 256x128 tile, BK=32, 2-phase, 2 blocks/CU ----------------
// Best-measured clean structure (233-237us, MfmaUtil ~24.5%, conflicts 0, occ ~42%).
template <bool OUT_BF16>
__global__ __launch_bounds__(512, 4) void gemm256(
    const u16* __restrict__ A, const u16* __restrict__ Bt,
    const float* __restrict__ bias, void* __restrict__ Cout,
    int M, int N, int K) {
  __shared__ u16 Al[2][256 * 32];  // 16 KB per buffer
  __shared__ u16 Bl[2][128 * 32];  //  8 KB per buffer

  const int Ntiles = N >> 7;
  const int nwg = (M >> 8) * Ntiles;
  int bid = (int)blockIdx.x;
  bid = (bid & 7) * (nwg >> 3) + (bid >> 3);  // bijective: nwg % 8 == 0
  const int mt = bid / Ntiles, ntl = bid % Ntiles;
  const int m0 = mt << 8, n0 = ntl << 7;

  const int tid = (int)threadIdx.x;
  const int lane = tid & 63;
  const int wid = tid >> 6;
  const int wm = wid >> 1, wn = wid & 1;  // 4 x 2 wave grid, per-wave 64x64
  const int lr = lane & 15, lg = lane >> 4;

  const int srow = lane >> 2;
  const int sslot = (lane & 3) ^ ((lane >> 3) & 3);
  const u16* Abase = A + (size_t)(m0 + wid * 32 + srow) * K + sslot * 8;
  const u16* Bbase = Bt + (size_t)(n0 + wid * 16 + srow) * K + sslot * 8;

  auto stage = [&](u16* da, u16* db, int t) {
    const int k0 = t << 5;
    gload_lds16(Abase + k0, (char*)da + wid * 2048);
    gload_lds16(Abase + ((size_t)K << 4) + k0, (char*)da + wid * 2048 + 1024);
    gload_lds16(Bbase + k0, (char*)db + wid * 1024);
  };

  auto ldsF = [&](const u16* base, int row) -> frag_t {
    const int phys = lg ^ ((row >> 1) & 3);
    return *(const frag_t*)(base + (size_t)row * 32 + phys * 8);
  };

  f32x4 zero4 = {0.f, 0.f, 0.f, 0.f};
  f32x4 acc[4][4];
#pragma unroll
  for (int i = 0; i < 4; ++i)
#pragma unroll
    for (int j = 0; j < 4; ++j) acc[i][j] = zero4;

  const int nt = K >> 5;  // K-tiles, >= 2
  const int ar0 = wm * 64 + lr;
  const int br0 = wn * 64 + lr;

  stage(&Al[0][0], &Bl[0][0], 0);
  stage(&Al[1][0], &Bl[1][0], 1);
  asm volatile("s_waitcnt vmcnt(3)" ::: "memory");
  __builtin_amdgcn_s_barrier();

  for (int t = 0; t < nt; ++t) {
    const int cur = t & 1;
    const u16* al = &Al[cur][0];
    const u16* bl = &Bl[cur][0];
    if (t >= 1 && t + 1 < nt)
      stage(&Al[cur ^ 1][0], &Bl[cur ^ 1][0], t + 1);
    frag_t a[4], b[4];
#pragma unroll
    for (int i = 0; i < 4; ++i) a[i] = ldsF(al, ar0 + i * 16);
#pragma unroll
    for (int j = 0; j < 4; ++j) b[j] = ldsF(bl, br0 + j * 16);
#pragma unroll
    for (int i = 0; i < 4; ++i)
#pragma unroll
      for (int j = 0; j < 4; ++j)
        acc[i][j] = mfma_bf16(a[i], b[j], acc[i][j]);
    if (t + 1 < nt) {
      asm volatile("s_waitcnt vmcnt(0)" ::: "memory");
      __builtin_amdgcn_s_barrier();
    }
  }

  float bvv[4];
#pragma unroll
  for (int bj = 0; bj < 4; ++bj) bvv[bj] = bias[n0 + wn * 64 + bj * 16 + lr];
#pragma unroll
  for (int ai = 0; ai < 4; ++ai) {
    const int rbase = m0 + wm * 64 + ai * 16 + lg * 4;
#pragma unroll
    for (int rr = 0; rr < 4; ++rr) {
      const int row = rbase + rr;
#pragma unroll
      for (int bj = 0; bj < 4; ++bj) {
        const int cb = n0 + wn * 64 + bj * 16;
        const float val = acc[ai][bj][rr] + bvv[bj];
        if constexpr (OUT_BF16) {
          u32 me = f2bf(val);
          u32 d0 = me | (__shfl_xor(me, 1) << 16);
          u32 d1 = __shfl_xor(d0, 2);
          if ((lane & 3) == 0) {
            uint2 o; o.x = d0; o.y = d1;
            *(uint2*)((u16*)Cout + (size_t)row * N + cb + (lr & 12)) = o;
          }
        } else {
          float v0 = val;
          float v1 = __shfl_xor(v0, 1);
          float v2 = __shfl_xor(v0, 2);
          float v3 = __shfl_xor(v1, 2);
          if ((lane & 3) == 0) {
            float4 o; o.x = v0; o.y = v1; o.z = v2; o.w = v3;
            *(float4*)((float*)Cout + (size_t)row * N + cb + (lr & 12)) = o;
          }
        }
      }
    }
  }
}

// ---------------- attention: 4 q-tiles per block; K/V from merged [1232][2048] ------
__global__ __launch_bounds__(256) void attn_kernel(
    const u16* __restrict__ Q, const u16* __restrict__ KV,
    u16* __restrict__ O) {
  __shared__ u16 Kl[96][72];
  __shared__ u16 Vt[64][104];

  const int bid = blockIdx.x;   // 4096 = 16 qgroups x 16 heads x 16 batch
  const int qt0 = bid & 15;
  const int h = (bid >> 4) & 15;
  const int b = bid >> 8;
  const int tid = threadIdx.x;

#pragma unroll
  for (int it = 0; it < 3; ++it) {
    const int idx = tid + it * 256;
    const int key = idx >> 3, s = idx & 7;
    uint4 val{0u, 0u, 0u, 0u};
    if (key < 77)
      val = *(const uint4*)(KV + ((size_t)(b * 77 + key)) * 2048 + h * 64 + s * 8);
    *(uint4*)(&Kl[key][s * 8]) = val;
  }
#pragma unroll
  for (int it = 0; it < 3; ++it) {
    const int idx = tid + it * 256;
    if (idx < 616) {
      const int key = idx >> 3, s = idx & 7;
      const uint4 v4 = *(const uint4*)(KV + ((size_t)(b * 77 + key)) * 2048 +
                                       1024 + h * 64 + s * 8);
      const u16* e = (const u16*)&v4;
#pragma unroll
      for (int j = 0; j < 8; ++j) Vt[s * 8 + j][key] = e[j];
    }
  }
#pragma unroll
  for (int it = 0; it < 5; ++it) {
    const int idx = tid + it * 256;
    if (idx < 1216) {
      const int d = idx / 19, kk = 77 + idx % 19;
      Vt[d][kk] = 0;
    }
  }
  __syncthreads();

  const int lane = tid & 63;
  const int wv = tid >> 6;
  const int lr = lane & 15;
  const int lg = lane >> 4;
  f32x4 zero4 = {0.f, 0.f, 0.f, 0.f};

  for (int q4 = 0; q4 < 4; ++q4) {
    const int qt = qt0 * 4 + q4;

    const size_t qrow = (size_t)(b * 4096 + qt * 64 + wv * 16 + lr) * 1024 + h * 64;
    frag_t qf[2];
#pragma unroll
    for (int ks = 0; ks < 2; ++ks)
      qf[ks] = *(const frag_t*)(Q + qrow + ks * 32 + lg * 8);

    f32x4 sa[5] = {zero4, zero4, zero4, zero4, zero4};
#pragma unroll
    for (int ks = 0; ks < 2; ++ks) {
#pragma unroll
      for (int kt = 0; kt < 5; ++kt) {
        frag_t kf = *(const frag_t*)(&Kl[kt * 16 + lr][ks * 32 + lg * 8]);
        sa[kt] = mfma_bf16(kf, qf[ks], sa[kt]);
      }
    }

    float p[5][4];
    float mx = -3.0e38f;
#pragma unroll
    for (int kt = 0; kt < 5; ++kt)
#pragma unroll
      for (int r = 0; r < 4; ++r) {
        const int key = kt * 16 + lg * 4 + r;
        float s = sa[kt][r] * 0.125f;
        if (key >= 77) s = -3.0e38f;
        p[kt][r] = s;
        mx = fmaxf(mx, s);
      }
    mx = fmaxf(mx, __shfl_xor(mx, 16));
    mx = fmaxf(mx, __shfl_xor(mx, 32));
    float sum = 0.f;
#pragma unroll
    for (int kt = 0; kt < 5; ++kt)
#pragma unroll
      for (int r = 0; r < 4; ++r) {
        const float e = __expf(p[kt][r] - mx);
        p[kt][r] = e;
        sum += e;
      }
    sum += __shfl_xor(sum, 16);
    sum += __shfl_xor(sum, 32);
    const float rden = 1.0f / sum;
#pragma unroll
    for (int kt = 0; kt < 5; ++kt)
#pragma unroll
      for (int r = 0; r < 4; ++r) p[kt][r] *= rden;

    union FP { frag_t v; u16 e[8]; };
    frag_t pa[3];
#pragma unroll
    for (int kb = 0; kb < 3; ++kb) {
      FP f;
#pragma unroll
      for (int j = 0; j < 8; ++j) {
        const int kt = 2 * kb + (j >> 2);
        f.e[j] = (kt < 5) ? f2bf(p[kt][j & 3]) : (u16)0;
      }
      pa[kb] = f.v;
    }

    f32x4 oa[4] = {zero4, zero4, zero4, zero4};
#pragma unroll
    for (int nt = 0; nt < 4; ++nt) {
      const int d = nt * 16 + lr;
#pragma unroll
      for (int kb = 0; kb < 3; ++kb) {
        const int key0 = kb * 32 + lg * 4;
        FP vb;
        *(uint2*)(&vb.e[0]) = *(const uint2*)(&Vt[d][key0]);
        *(uint2*)(&vb.e[4]) = *(const uint2*)(&Vt[d][key0 + 16]);
        oa[nt] = mfma_bf16(pa[kb], vb.v, oa[nt]);
      }
    }

#pragma unroll
    for (int nt = 0; nt < 4; ++nt)
#pragma unroll
      for (int r = 0; r < 4; ++r) {
        const int qr = wv * 16 + lg * 4 + r;
        u32 me = f2bf(oa[nt][r]);
        u32 other = __shfl_xor(me, 1);
        if ((lane & 1) == 0) {
          *(u32*)(O + ((size_t)(b * 4096 + qt * 64 + qr)) * 1024 + h * 64 +
                  nt * 16 + lr) = me | (other << 16);
        }
      }
  }
}

// ---------------- launch ----------------
extern "C" void kernel_launch(void* const* d_in, const int* in_sizes, int n_in,
                              void* d_out, int out_size, void* d_ws, size_t ws_size,
                              hipStream_t stream) {
  const float* x  = (const float*)d_in[0];
  const float* p  = (const float*)d_in[1];
  const float* Wq = (const float*)d_in[2];
  const float* bq = (const float*)d_in[3];
  const float* Wk = (const float*)d_in[4];
  const float* bk = (const float*)d_in[5];
  const float* Wv = (const float*)d_in[6];
  const float* bv = (const float*)d_in[7];
  const float* Ww = (const float*)d_in[8];
  const float* bw = (const float*)d_in[9];

  char* ws = (char*)d_ws;
  if (ws_size < 281034752ULL) return;

  u16* x_bf  = (u16*)(ws + 0);          // 65536x1024 bf16; reused as attn_out
  u16* q_bf  = (u16*)(ws + 134217728);  // 65536x1024
  u16* wq_t  = (u16*)(ws + 268435456);  // [1024][1024]
  u16* ww_t  = (u16*)(ws + 270532608);  // [1024][1024]
  u16* wkv_t = (u16*)(ws + 272629760);  // [2048][512] (K rows 0-1023, V rows 1024-2047)
  u16* p_bf  = (u16*)(ws + 274726912);  // 1232x512
  u16* kv_bf = (u16*)(ws + 275988480);  // [1232][2048] (K cols 0-1023, V cols 1024-2047)

  // one prep launch: cast x, cast p, transpose all 4 weights
  prep_kernel<<<36148, 256, 0, stream>>>(x, p, Wq, Ww, Wk, Wv,
                                         x_bf, p_bf, wq_t, ww_t, wkv_t);
  // merged K/V projection: [1232][2048] = p_bf @ wkv_t^T + [bk;bv]  (160 blocks)
  gemm_bt<true><<<160, 256, 0, stream>>>(p_bf, wkv_t, bk, bv, kv_bf,
                                         1232, 2048, 512, 10, 16);
  // Q projection: 256x128 tile, 2 blocks/CU (2048 blocks)
  gemm256<true><<<2048, 512, 0, stream>>>(x_bf, wq_t, bq, q_bf, 65536, 1024, 1024);
  // attention: 4 q-tiles per block (4096 blocks), K/V from merged buffer
  attn_kernel<<<4096, 256, 0, stream>>>(q_bf, kv_bf, x_bf);
  // out projection -> fp32
  gemm256<false><<<2048, 512, 0, stream>>>(x_bf, ww_t, bw, d_out, 65536, 1024, 1024);
}

// Round 15
// 553.369 us; speedup vs baseline: 1.4531x; 1.0649x over previous
//
#include <hip/hip_runtime.h>
#include <cstdint>
#include <type_traits>

typedef uint16_t u16;
typedef uint32_t u32;
typedef __attribute__((ext_vector_type(4))) float f32x4;
typedef __attribute__((ext_vector_type(8))) __bf16 vbf8;
typedef __attribute__((ext_vector_type(8))) short vs8;

// ---- MFMA operand-type hedge: prefer v8bf16, fall back to v8i16 ----
template <typename T, typename = void>
struct CanMfma : std::false_type {};
template <typename T>
struct CanMfma<T, std::void_t<decltype(__builtin_amdgcn_mfma_f32_16x16x32_bf16(
    std::declval<T>(), std::declval<T>(), std::declval<f32x4>(), 0, 0, 0))>>
    : std::true_type {};
typedef std::conditional_t<CanMfma<vbf8>::value, vbf8, vs8> frag_t;

__device__ __forceinline__ f32x4 mfma_bf16(frag_t a, frag_t b, f32x4 c) {
  return __builtin_amdgcn_mfma_f32_16x16x32_bf16(a, b, c, 0, 0, 0);
}

__device__ __forceinline__ u16 f2bf(float f) {
  u32 u = __builtin_bit_cast(u32, f);
  u32 r = (u + 0x7FFFu + ((u >> 16) & 1u)) >> 16;
  return (u16)r;
}

__device__ __forceinline__ void gload_lds16(const void* g, void* l) {
  __builtin_amdgcn_global_load_lds(
      (const __attribute__((address_space(1))) void*)g,
      (__attribute__((address_space(3))) void*)l, 16, 0, 0);
}

#define SB0() __builtin_amdgcn_sched_barrier(0)

// ---------------- merged prep: cast_x + cast_p + 4 weight transposes ----------------
__device__ __forceinline__ void transpose_body(
    const float* __restrict__ in, u16* __restrict__ out, int K, int N,
    int k0, int n0, float (*tile)[33]) {
  const int tr = threadIdx.x >> 5, tc = threadIdx.x & 31;
#pragma unroll
  for (int i = 0; i < 4; ++i)
    tile[tr + i * 8][tc] = in[(size_t)(k0 + tr + i * 8) * N + (n0 + tc)];
  __syncthreads();
#pragma unroll
  for (int i = 0; i < 4; ++i)
    out[(size_t)(n0 + tr + i * 8) * K + (k0 + tc)] = f2bf(tile[tc][tr + i * 8]);
}

__global__ __launch_bounds__(256) void prep_kernel(
    const float* __restrict__ x, const float* __restrict__ p,
    const float* __restrict__ Wq, const float* __restrict__ Ww,
    const float* __restrict__ Wk, const float* __restrict__ Wv,
    u16* __restrict__ x_bf, u16* __restrict__ p_bf,
    u16* __restrict__ wq_t, u16* __restrict__ ww_t, u16* __restrict__ wkv_t) {
  __shared__ float tile[32][33];
  const int bid = blockIdx.x;
  if (bid < 32768) {
    const size_t i = (size_t)bid * 256 + threadIdx.x;
    const float4 a  = ((const float4*)x)[i * 2];
    const float4 b2 = ((const float4*)x)[i * 2 + 1];
    uint4 o;
    o.x = (u32)f2bf(a.x)  | ((u32)f2bf(a.y)  << 16);
    o.y = (u32)f2bf(a.z)  | ((u32)f2bf(a.w)  << 16);
    o.z = (u32)f2bf(b2.x) | ((u32)f2bf(b2.y) << 16);
    o.w = (u32)f2bf(b2.z) | ((u32)f2bf(b2.w) << 16);
    ((uint4*)x_bf)[i] = o;
  } else if (bid < 33076) {
    const int i = (bid - 32768) * 256 + threadIdx.x;
    if (i < 78848) {
      const float4 a  = ((const float4*)p)[(size_t)i * 2];
      const float4 b2 = ((const float4*)p)[(size_t)i * 2 + 1];
      uint4 o;
      o.x = (u32)f2bf(a.x)  | ((u32)f2bf(a.y)  << 16);
      o.y = (u32)f2bf(a.z)  | ((u32)f2bf(a.w)  << 16);
      o.z = (u32)f2bf(b2.x) | ((u32)f2bf(b2.y) << 16);
      o.w = (u32)f2bf(b2.z) | ((u32)f2bf(b2.w) << 16);
      ((uint4*)p_bf)[(size_t)i] = o;
    }
  } else if (bid < 35124) {
    const bool isQ = bid < 34100;
    const int r = (bid - (isQ ? 33076 : 34100));
    transpose_body(isQ ? Wq : Ww, isQ ? wq_t : ww_t, 1024, 1024,
                   (r & 31) * 32, (r >> 5) * 32, tile);
  } else {
    const bool isK = bid < 35636;
    const int r = (bid - (isK ? 35124 : 35636));
    transpose_body(isK ? Wk : Wv, isK ? wkv_t : (wkv_t + 1024 * 512), 512, 1024,
                   (r & 15) * 32, (r >> 4) * 32, tile);
  }
}

// ---------------- small GEMM (128^2, 2-phase dbuf): merged K/V projection ------------
template <bool OUT_BF16>
__global__ __launch_bounds__(256) void gemm_bt(
    const u16* __restrict__ A, const u16* __restrict__ Bt,
    const float* __restrict__ biasA, const float* __restrict__ biasB,
    void* __restrict__ Cout,
    int M, int N, int K, int Mtiles, int Ntiles) {
  __shared__ char Al[2][128 * 32 * 2];
  __shared__ char Bl[2][128 * 32 * 2];

  const int nwg = Mtiles * Ntiles;
  int bid = (int)blockIdx.x;
  bid = (bid & 7) * (nwg >> 3) + (bid >> 3);
  const int mt = bid / Ntiles, nt = bid % Ntiles;
  const int m0 = mt * 128, n0 = nt * 128;

  const int tid = (int)threadIdx.x;
  const int lane = tid & 63;
  const int wv = tid >> 6;
  const int wm = wv & 1, wn = wv >> 1;
  const int lr = lane & 15, lg = lane >> 4;
  const int rsub = lane >> 2;
  const int slot = lane & 3;
  const int rb0 = n0 + rsub;

  auto stage = [&](int buf, int t) {
    const int k0 = t << 5;
#pragma unroll
    for (int c = 0; c < 2; ++c) {
      const int ci = c * 4 + wv;
      int rra = m0 + ci * 16 + rsub;
      if (rra >= M) rra = M - 1;
      gload_lds16(A + (size_t)rra * K + k0 + slot * 8, Al[buf] + ci * 1024);
      const int rrb = rb0 + ci * 16;
      gload_lds16(Bt + (size_t)rrb * K + k0 + slot * 8, Bl[buf] + ci * 1024);
    }
  };

  f32x4 zero4 = {0.f, 0.f, 0.f, 0.f};
  f32x4 acc[4][4];
#pragma unroll
  for (int i = 0; i < 4; ++i)
#pragma unroll
    for (int j = 0; j < 4; ++j) acc[i][j] = zero4;

  const int nk = K >> 5;
  int cur = 0;
  stage(0, 0);
  __syncthreads();

  for (int t = 0; t < nk; ++t) {
    if (t + 1 < nk) stage(cur ^ 1, t + 1);
    frag_t af[4], bf[4];
#pragma unroll
    for (int i = 0; i < 4; ++i) {
      af[i] = *(const frag_t*)(Al[cur] + (wm * 64 + i * 16 + lr) * 64 + lg * 16);
      bf[i] = *(const frag_t*)(Bl[cur] + (wn * 64 + i * 16 + lr) * 64 + lg * 16);
    }
#pragma unroll
    for (int i = 0; i < 4; ++i)
#pragma unroll
      for (int j = 0; j < 4; ++j)
        acc[i][j] = mfma_bf16(af[i], bf[j], acc[i][j]);
    __syncthreads();
    cur ^= 1;
  }

#pragma unroll
  for (int j = 0; j < 4; ++j) {
    const int col = n0 + wn * 64 + j * 16 + lr;
    const float bv = (col < 1024) ? biasA[col] : biasB[col - 1024];
#pragma unroll
    for (int i = 0; i < 4; ++i) {
      const int rbase = m0 + wm * 64 + i * 16 + lg * 4;
#pragma unroll
      for (int r = 0; r < 4; ++r) {
        const int row = rbase + r;
        const float val = acc[i][j][r] + bv;
        if constexpr (OUT_BF16) {
          u32 me = f2bf(val);
          u32 other = __shfl_xor(me, 1);
          if ((lane & 1) == 0 && row < M) {
            *(u32*)((u16*)Cout + (size_t)row * N + col) = me | (other << 16);
          }
        } else {
          if (row < M) ((float*)Cout)[(size_t)row * N + col] = val;
        }
      }
    }
  }
}

// ---------------- big GEMM (proven): 256x128 tile, BK=32, 2-phase, 2 blocks/CU ------
template <bool OUT_BF16>
__global__ __launch_bounds__(512, 4) void gemm256(
    const u16* __restrict__ A, const u16* __restrict__ Bt,
    const float* __restrict__ bias, void* __restrict__ Cout,
    int M, int N, int K) {
  __shared__ u16 Al[2][256 * 32];
  __shared__ u16 Bl[2][128 * 32];

  const int Ntiles = N >> 7;
  const int nwg = (M >> 8) * Ntiles;
  int bid = (int)blockIdx.x;
  bid = (bid & 7) * (nwg >> 3) + (bid >> 3);
  const int mt = bid / Ntiles, ntl = bid % Ntiles;
  const int m0 = mt << 8, n0 = ntl << 7;

  const int tid = (int)threadIdx.x;
  const int lane = tid & 63;
  const int wid = tid >> 6;
  const int wm = wid >> 1, wn = wid & 1;
  const int lr = lane & 15, lg = lane >> 4;

  const int srow = lane >> 2;
  const int sslot = (lane & 3) ^ ((lane >> 3) & 3);
  const u16* Abase = A + (size_t)(m0 + wid * 32 + srow) * K + sslot * 8;
  const u16* Bbase = Bt + (size_t)(n0 + wid * 16 + srow) * K + sslot * 8;

  auto stage = [&](u16* da, u16* db, int t) {
    const int k0 = t << 5;
    gload_lds16(Abase + k0, (char*)da + wid * 2048);
    gload_lds16(Abase + ((size_t)K << 4) + k0, (char*)da + wid * 2048 + 1024);
    gload_lds16(Bbase + k0, (char*)db + wid * 1024);
  };

  auto ldsF = [&](const u16* base, int row) -> frag_t {
    const int phys = lg ^ ((row >> 1) & 3);
    return *(const frag_t*)(base + (size_t)row * 32 + phys * 8);
  };

  f32x4 zero4 = {0.f, 0.f, 0.f, 0.f};
  f32x4 acc[4][4];
#pragma unroll
  for (int i = 0; i < 4; ++i)
#pragma unroll
    for (int j = 0; j < 4; ++j) acc[i][j] = zero4;

  const int nt = K >> 5;
  const int ar0 = wm * 64 + lr;
  const int br0 = wn * 64 + lr;

  stage(&Al[0][0], &Bl[0][0], 0);
  stage(&Al[1][0], &Bl[1][0], 1);
  asm volatile("s_waitcnt vmcnt(3)" ::: "memory");
  __builtin_amdgcn_s_barrier();

  for (int t = 0; t < nt; ++t) {
    const int cur = t & 1;
    const u16* al = &Al[cur][0];
    const u16* bl = &Bl[cur][0];
    if (t >= 1 && t + 1 < nt)
      stage(&Al[cur ^ 1][0], &Bl[cur ^ 1][0], t + 1);
    frag_t a[4], b[4];
#pragma unroll
    for (int i = 0; i < 4; ++i) a[i] = ldsF(al, ar0 + i * 16);
#pragma unroll
    for (int j = 0; j < 4; ++j) b[j] = ldsF(bl, br0 + j * 16);
#pragma unroll
    for (int i = 0; i < 4; ++i)
#pragma unroll
      for (int j = 0; j < 4; ++j)
        acc[i][j] = mfma_bf16(a[i], b[j], acc[i][j]);
    if (t + 1 < nt) {
      asm volatile("s_waitcnt vmcnt(0)" ::: "memory");
      __builtin_amdgcn_s_barrier();
    }
  }

  float bvv[4];
#pragma unroll
  for (int bj = 0; bj < 4; ++bj) bvv[bj] = bias[n0 + wn * 64 + bj * 16 + lr];
#pragma unroll
  for (int ai = 0; ai < 4; ++ai) {
    const int rbase = m0 + wm * 64 + ai * 16 + lg * 4;
#pragma unroll
    for (int rr = 0; rr < 4; ++rr) {
      const int row = rbase + rr;
#pragma unroll
      for (int bj = 0; bj < 4; ++bj) {
        const int cb = n0 + wn * 64 + bj * 16;
        const float val = acc[ai][bj][rr] + bvv[bj];
        if constexpr (OUT_BF16) {
          u32 me = f2bf(val);
          u32 d0 = me | (__shfl_xor(me, 1) << 16);
          u32 d1 = __shfl_xor(d0, 2);
          if ((lane & 3) == 0) {
            uint2 o; o.x = d0; o.y = d1;
            *(uint2*)((u16*)Cout + (size_t)row * N + cb + (lr & 12)) = o;
          }
        } else {
          float v0 = val;
          float v1 = __shfl_xor(v0, 1);
          float v2 = __shfl_xor(v0, 2);
          float v3 = __shfl_xor(v1, 2);
          if ((lane & 3) == 0) {
            float4 o; o.x = v0; o.y = v1; o.z = v2; o.w = v3;
            *(float4*)((float*)Cout + (size_t)row * N + cb + (lr & 12)) = o;
          }
        }
      }
    }
  }
}

// ---------------- m201-faithful 8-phase GEMM: 256^2, BK=64, 8 waves (2Mx4N) ---------
// Derived ledger: A halves = 64-row stripes, half=(r>>6)&1 (Ah0 read P0, Ah1 P2);
// B halves = 32-row stripes, half=(r>>5)&1 (Bh0 read P0, Bh1 P1). Frees: Ah0,Bh0
// after P0; Bh1 after P1; Ah1 after P2. Stage stream (1 half/phase, 3-half lead):
// tau.P0: Ah1(tau+1) -> other buf; P1: Ah0(tau+2); P2: Bh0(tau+2); P3: Bh1(tau+2)
// -> current buf (= (tau+2)&1). vmcnt(6) ONLY at P3 (leaves exactly the 3 halves of
// tau+2 in flight; publishes everything of tau+1). Every publish >= 4 phases before
// its read. LDS 128KB (1 blk/CU). Swizzle: phys slot = (ks*4+lg) ^ (r&7), source
// pre-swizzled (rule 21). lgkmcnt(8) after P0's 12 ds_reads (spec); rule-18 SB0s.
template <bool OUT_BF16>
__global__ __launch_bounds__(512, 1) void gemm8p(
    const u16* __restrict__ A, const u16* __restrict__ Bt,
    const float* __restrict__ bias, void* __restrict__ Cout,
    int M, int N, int K) {
  __shared__ u16 Al[2][256 * 64];  // [half(8192)][stripe-in-half(4096)] layout below
  __shared__ u16 Bl[2][256 * 64];  // [half(8192)][32-stripe-in-half(2048)]

  const int Ntiles = N >> 8;
  const int nwg = (M >> 8) * Ntiles;
  int bid = (int)blockIdx.x;
  bid = (bid & 7) * (nwg >> 3) + (bid >> 3);  // bijective: nwg % 8 == 0
  const int mt = bid / Ntiles, ntl = bid % Ntiles;
  const int m0 = mt << 8, n0 = ntl << 8;

  const int tid = (int)threadIdx.x;
  const int lane = tid & 63;
  const int wid = tid >> 6;
  const int wm = wid >> 2, wn = wid & 3;  // 2M x 4N; per-wave out 128x64
  const int lr = lane & 15, lg = lane >> 4;
  const int sslot = (lane & 7) ^ (lane >> 3);
  const int lrow = lane >> 3;

  // stage A half (64-row stripes {half, half+2}), one gload per stripe per wave
  auto stageA = [&](u16* dst, int half, int t) {
#pragma unroll
    for (int sub = 0; sub < 2; ++sub) {
      const int s = half + sub * 2;
      const u16* g = A + (size_t)(m0 + s * 64 + wid * 8 + lrow) * K + t * 64 + sslot * 8;
      u16* l = dst + (s & 1) * 8192 + (s >> 1) * 4096 + wid * 512;
      gload_lds16(g, l);
    }
  };
  // stage B half (32-row stripes {half, half+2, half+4, half+6}); per wave 2 gloads
  auto stageB = [&](u16* dst, int half, int t) {
#pragma unroll
    for (int sub = 0; sub < 2; ++sub) {
      const int ub = wid * 16 + sub * 8;  // within-half linear row base
      const int r = n0 + (ub >> 5) * 64 + half * 32 + (ub & 31) + lrow;
      const u16* g = Bt + (size_t)r * K + t * 64 + sslot * 8;
      u16* l = dst + half * 8192 + ub * 64;
      gload_lds16(g, l);
    }
  };

  auto ldsA = [&](const u16* base, int r, int ks) -> frag_t {
    const int off = ((r >> 6) & 1) * 8192 + (r >> 7) * 4096 + (r & 63) * 64 +
                    ((((ks) << 2) + lg) ^ (r & 7)) * 8;
    return *(const frag_t*)(base + off);
  };
  auto ldsB = [&](const u16* base, int r, int ks) -> frag_t {
    const int off = ((r >> 5) & 1) * 8192 + (r >> 6) * 2048 + (r & 31) * 64 +
                    ((((ks) << 2) + lg) ^ (r & 7)) * 8;
    return *(const frag_t*)(base + off);
  };

  f32x4 acc[8][4];
#pragma unroll
  for (int i = 0; i < 8; ++i)
#pragma unroll
    for (int j = 0; j < 4; ++j)
#pragma unroll
      for (int r = 0; r < 4; ++r) acc[i][j][r] = 0.f;

  frag_t aR[4][2], b0R[2][2], b1R[2][2];
  auto mmq = [&](frag_t (&bb)[2][2], int mo, int no) {
    __builtin_amdgcn_s_setprio(1);
#pragma unroll
    for (int i = 0; i < 4; ++i)
#pragma unroll
      for (int j = 0; j < 2; ++j) {
        acc[mo + i][no + j] = mfma_bf16(aR[i][0], bb[j][0], acc[mo + i][no + j]);
        acc[mo + i][no + j] = mfma_bf16(aR[i][1], bb[j][1], acc[mo + i][no + j]);
      }
    __builtin_amdgcn_s_setprio(0);
  };

  const int nt = K >> 6;  // >= 3
  const int arow = wm * 128 + lr;
  const int brow = wn * 64 + lr;

  // prologue: tile0 all 4 halves; tile1's Ah0, Bh0, Bh1; vmcnt(6) -> tile0 landed
  stageA(&Al[0][0], 0, 0); stageA(&Al[0][0], 1, 0);
  stageB(&Bl[0][0], 0, 0); stageB(&Bl[0][0], 1, 0);
  stageA(&Al[1][0], 0, 1);
  stageB(&Bl[1][0], 0, 1); stageB(&Bl[1][0], 1, 1);
  asm volatile("s_waitcnt vmcnt(6)" ::: "memory");
  __builtin_amdgcn_s_barrier();

  for (int t = 0; t < nt; ++t) {
    const int cur = t & 1;
    const u16* bA = &Al[cur][0];
    const u16* bB = &Bl[cur][0];
    // ---- P0: read a(mf0-3) + b0 (12 reads); stage Ah1(t+1) -> other buf
#pragma unroll
    for (int i = 0; i < 4; ++i) {
      aR[i][0] = ldsA(bA, arow + i * 16, 0);
      aR[i][1] = ldsA(bA, arow + i * 16, 1);
    }
#pragma unroll
    for (int j = 0; j < 2; ++j) {
      b0R[j][0] = ldsB(bB, brow + j * 16, 0);
      b0R[j][1] = ldsB(bB, brow + j * 16, 1);
    }
    if (t + 1 < nt) stageA(&Al[cur ^ 1][0], 1, t + 1);
    asm volatile("s_waitcnt lgkmcnt(8)" ::: "memory");
    SB0();
    __builtin_amdgcn_s_barrier();
    asm volatile("s_waitcnt lgkmcnt(0)" ::: "memory");
    SB0();
    mmq(b0R, 0, 0);
    __builtin_amdgcn_s_barrier();
    // ---- P1: read b1 (4); stage Ah0(t+2) -> current buf
#pragma unroll
    for (int j = 0; j < 2; ++j) {
      b1R[j][0] = ldsB(bB, brow + 32 + j * 16, 0);
      b1R[j][1] = ldsB(bB, brow + 32 + j * 16, 1);
    }
    if (t + 2 < nt) stageA(&Al[cur][0], 0, t + 2);
    SB0();
    __builtin_amdgcn_s_barrier();
    asm volatile("s_waitcnt lgkmcnt(0)" ::: "memory");
    SB0();
    mmq(b1R, 0, 2);
    __builtin_amdgcn_s_barrier();
    // ---- P2: read a(mf4-7) (8); stage Bh0(t+2)
#pragma unroll
    for (int i = 0; i < 4; ++i) {
      aR[i][0] = ldsA(bA, arow + 64 + i * 16, 0);
      aR[i][1] = ldsA(bA, arow + 64 + i * 16, 1);
    }
    if (t + 2 < nt) stageB(&Bl[cur][0], 0, t + 2);
    SB0();
    __builtin_amdgcn_s_barrier();
    asm volatile("s_waitcnt lgkmcnt(0)" ::: "memory");
    SB0();
    mmq(b1R, 4, 2);
    __builtin_amdgcn_s_barrier();
    // ---- P3: no reads; stage Bh1(t+2); MFMA; counted drain (never 0 mid-loop)
    if (t + 2 < nt) stageB(&Bl[cur][0], 1, t + 2);
    mmq(b0R, 4, 0);
    if (t + 2 < nt)
      asm volatile("s_waitcnt vmcnt(6)" ::: "memory");
    else if (t + 1 < nt)
      asm volatile("s_waitcnt vmcnt(0)" ::: "memory");
    if (t + 1 < nt) __builtin_amdgcn_s_barrier();
  }

  // epilogue: row = m0+wm*128+mf*16+lg*4+rr ; col = n0+wn*64+nf*16+lr
  float bvv[4];
#pragma unroll
  for (int nf = 0; nf < 4; ++nf) bvv[nf] = bias[n0 + wn * 64 + nf * 16 + lr];
#pragma unroll
  for (int mf = 0; mf < 8; ++mf) {
    const int rbase = m0 + wm * 128 + mf * 16 + lg * 4;
#pragma unroll
    for (int rr = 0; rr < 4; ++rr) {
      const int row = rbase + rr;
#pragma unroll
      for (int nf = 0; nf < 4; ++nf) {
        const int cb = n0 + wn * 64 + nf * 16;
        const float val = acc[mf][nf][rr] + bvv[nf];
        if constexpr (OUT_BF16) {
          u32 me = f2bf(val);
          u32 d0 = me | (__shfl_xor(me, 1) << 16);
          u32 d1 = __shfl_xor(d0, 2);
          if ((lane & 3) == 0) {
            uint2 o; o.x = d0; o.y = d1;
            *(uint2*)((u16*)Cout + (size_t)row * N + cb + (lr & 12)) = o;
          }
        } else {
          float v0 = val;
          float v1 = __shfl_xor(v0, 1);
          float v2 = __shfl_xor(v0, 2);
          float v3 = __shfl_xor(v1, 2);
          if ((lane & 3) == 0) {
            float4 o; o.x = v0; o.y = v1; o.z = v2; o.w = v3;
            *(float4*)((float*)Cout + (size_t)row * N + cb + (lr & 12)) = o;
          }
        }
      }
    }
  }
}

// ---------------- attention: 4 q-tiles per block; K/V from merged [1232][2048] ------
__global__ __launch_bounds__(256) void attn_kernel(
    const u16* __restrict__ Q, const u16* __restrict__ KV,
    u16* __restrict__ O) {
  __shared__ u16 Kl[96][72];
  __shared__ u16 Vt[64][104];

  const int bid = blockIdx.x;
  const int qt0 = bid & 15;
  const int h = (bid >> 4) & 15;
  const int b = bid >> 8;
  const int tid = threadIdx.x;

#pragma unroll
  for (int it = 0; it < 3; ++it) {
    const int idx = tid + it * 256;
    const int key = idx >> 3, s = idx & 7;
    uint4 val{0u, 0u, 0u, 0u};
    if (key < 77)
      val = *(const uint4*)(KV + ((size_t)(b * 77 + key)) * 2048 + h * 64 + s * 8);
    *(uint4*)(&Kl[key][s * 8]) = val;
  }
#pragma unroll
  for (int it = 0; it < 3; ++it) {
    const int idx = tid + it * 256;
    if (idx < 616) {
      const int key = idx >> 3, s = idx & 7;
      const uint4 v4 = *(const uint4*)(KV + ((size_t)(b * 77 + key)) * 2048 +
                                       1024 + h * 64 + s * 8);
      const u16* e = (const u16*)&v4;
#pragma unroll
      for (int j = 0; j < 8; ++j) Vt[s * 8 + j][key] = e[j];
    }
  }
#pragma unroll
  for (int it = 0; it < 5; ++it) {
    const int idx = tid + it * 256;
    if (idx < 1216) {
      const int d = idx / 19, kk = 77 + idx % 19;
      Vt[d][kk] = 0;
    }
  }
  __syncthreads();

  const int lane = tid & 63;
  const int wv = tid >> 6;
  const int lr = lane & 15;
  const int lg = lane >> 4;
  f32x4 zero4 = {0.f, 0.f, 0.f, 0.f};

  for (int q4 = 0; q4 < 4; ++q4) {
    const int qt = qt0 * 4 + q4;

    const size_t qrow = (size_t)(b * 4096 + qt * 64 + wv * 16 + lr) * 1024 + h * 64;
    frag_t qf[2];
#pragma unroll
    for (int ks = 0; ks < 2; ++ks)
      qf[ks] = *(const frag_t*)(Q + qrow + ks * 32 + lg * 8);

    f32x4 sa[5] = {zero4, zero4, zero4, zero4, zero4};
#pragma unroll
    for (int ks = 0; ks < 2; ++ks) {
#pragma unroll
      for (int kt = 0; kt < 5; ++kt) {
        frag_t kf = *(const frag_t*)(&Kl[kt * 16 + lr][ks * 32 + lg * 8]);
        sa[kt] = mfma_bf16(kf, qf[ks], sa[kt]);
      }
    }

    float p[5][4];
    float mx = -3.0e38f;
#pragma unroll
    for (int kt = 0; kt < 5; ++kt)
#pragma unroll
      for (int r = 0; r < 4; ++r) {
        const int key = kt * 16 + lg * 4 + r;
        float s = sa[kt][r] * 0.125f;
        if (key >= 77) s = -3.0e38f;
        p[kt][r] = s;
        mx = fmaxf(mx, s);
      }
    mx = fmaxf(mx, __shfl_xor(mx, 16));
    mx = fmaxf(mx, __shfl_xor(mx, 32));
    float sum = 0.f;
#pragma unroll
    for (int kt = 0; kt < 5; ++kt)
#pragma unroll
      for (int r = 0; r < 4; ++r) {
        const float e = __expf(p[kt][r] - mx);
        p[kt][r] = e;
        sum += e;
      }
    sum += __shfl_xor(sum, 16);
    sum += __shfl_xor(sum, 32);
    const float rden = 1.0f / sum;
#pragma unroll
    for (int kt = 0; kt < 5; ++kt)
#pragma unroll
      for (int r = 0; r < 4; ++r) p[kt][r] *= rden;

    union FP { frag_t v; u16 e[8]; };
    frag_t pa[3];
#pragma unroll
    for (int kb = 0; kb < 3; ++kb) {
      FP f;
#pragma unroll
      for (int j = 0; j < 8; ++j) {
        const int kt = 2 * kb + (j >> 2);
        f.e[j] = (kt < 5) ? f2bf(p[kt][j & 3]) : (u16)0;
      }
      pa[kb] = f.v;
    }

    f32x4 oa[4] = {zero4, zero4, zero4, zero4};
#pragma unroll
    for (int nt = 0; nt < 4; ++nt) {
      const int d = nt * 16 + lr;
#pragma unroll
      for (int kb = 0; kb < 3; ++kb) {
        const int key0 = kb * 32 + lg * 4;
        FP vb;
        *(uint2*)(&vb.e[0]) = *(const uint2*)(&Vt[d][key0]);
        *(uint2*)(&vb.e[4]) = *(const uint2*)(&Vt[d][key0 + 16]);
        oa[nt] = mfma_bf16(pa[kb], vb.v, oa[nt]);
      }
    }

#pragma unroll
    for (int nt = 0; nt < 4; ++nt)
#pragma unroll
      for (int r = 0; r < 4; ++r) {
        const int qr = wv * 16 + lg * 4 + r;
        u32 me = f2bf(oa[nt][r]);
        u32 other = __shfl_xor(me, 1);
        if ((lane & 1) == 0) {
          *(u32*)(O + ((size_t)(b * 4096 + qt * 64 + qr)) * 1024 + h * 64 +
                  nt * 16 + lr) = me | (other << 16);
        }
      }
  }
}

// ---------------- launch ----------------
extern "C" void kernel_launch(void* const* d_in, const int* in_sizes, int n_in,
                              void* d_out, int out_size, void* d_ws, size_t ws_size,
                              hipStream_t stream) {
  const float* x  = (const float*)d_in[0];
  const float* p  = (const float*)d_in[1];
  const float* Wq = (const float*)d_in[2];
  const float* bq = (const float*)d_in[3];
  const float* Wk = (const float*)d_in[4];
  const float* bk = (const float*)d_in[5];
  const float* Wv = (const float*)d_in[6];
  const float* bv = (const float*)d_in[7];
  const float* Ww = (const float*)d_in[8];
  const float* bw = (const float*)d_in[9];

  char* ws = (char*)d_ws;
  if (ws_size < 281034752ULL) return;

  u16* x_bf  = (u16*)(ws + 0);          // 65536x1024 bf16; reused as attn_out
  u16* q_bf  = (u16*)(ws + 134217728);  // 65536x1024
  u16* wq_t  = (u16*)(ws + 268435456);  // [1024][1024]
  u16* ww_t  = (u16*)(ws + 270532608);  // [1024][1024]
  u16* wkv_t = (u16*)(ws + 272629760);  // [2048][512]
  u16* p_bf  = (u16*)(ws + 274726912);  // 1232x512
  u16* kv_bf = (u16*)(ws + 275988480);  // [1232][2048]

  prep_kernel<<<36148, 256, 0, stream>>>(x, p, Wq, Ww, Wk, Wv,
                                         x_bf, p_bf, wq_t, ww_t, wkv_t);
  gemm_bt<true><<<160, 256, 0, stream>>>(p_bf, wkv_t, bk, bv, kv_bf,
                                         1232, 2048, 512, 10, 16);
  // Q projection: m201-faithful 8-phase kernel (hedged deployment)
  gemm8p<true><<<1024, 512, 0, stream>>>(x_bf, wq_t, bq, q_bf, 65536, 1024, 1024);
  attn_kernel<<<4096, 256, 0, stream>>>(q_bf, kv_bf, x_bf);
  // out projection: proven 2-phase kernel
  gemm256<false><<<2048, 512, 0, stream>>>(x_bf, ww_t, bw, d_out, 65536, 1024, 1024);
}

// Round 16
// 514.434 us; speedup vs baseline: 1.5631x; 1.0757x over previous
//
#include <hip/hip_runtime.h>
#include <cstdint>
#include <type_traits>

typedef uint16_t u16;
typedef uint32_t u32;
typedef __attribute__((ext_vector_type(4))) float f32x4;
typedef __attribute__((ext_vector_type(8))) __bf16 vbf8;
typedef __attribute__((ext_vector_type(8))) short vs8;

// ---- MFMA operand-type hedge: prefer v8bf16, fall back to v8i16 ----
template <typename T, typename = void>
struct CanMfma : std::false_type {};
template <typename T>
struct CanMfma<T, std::void_t<decltype(__builtin_amdgcn_mfma_f32_16x16x32_bf16(
    std::declval<T>(), std::declval<T>(), std::declval<f32x4>(), 0, 0, 0))>>
    : std::true_type {};
typedef std::conditional_t<CanMfma<vbf8>::value, vbf8, vs8> frag_t;

__device__ __forceinline__ f32x4 mfma_bf16(frag_t a, frag_t b, f32x4 c) {
  return __builtin_amdgcn_mfma_f32_16x16x32_bf16(a, b, c, 0, 0, 0);
}

__device__ __forceinline__ u16 f2bf(float f) {
  u32 u = __builtin_bit_cast(u32, f);
  u32 r = (u + 0x7FFFu + ((u >> 16) & 1u)) >> 16;
  return (u16)r;
}

__device__ __forceinline__ void gload_lds16(const void* g, void* l) {
  __builtin_amdgcn_global_load_lds(
      (const __attribute__((address_space(1))) void*)g,
      (__attribute__((address_space(3))) void*)l, 16, 0, 0);
}

#define SB0() __builtin_amdgcn_sched_barrier(0)

// ---------------- merged prep: cast_x + cast_p + 4 weight transposes ----------------
__device__ __forceinline__ void transpose_body(
    const float* __restrict__ in, u16* __restrict__ out, int K, int N,
    int k0, int n0, float (*tile)[33]) {
  const int tr = threadIdx.x >> 5, tc = threadIdx.x & 31;
#pragma unroll
  for (int i = 0; i < 4; ++i)
    tile[tr + i * 8][tc] = in[(size_t)(k0 + tr + i * 8) * N + (n0 + tc)];
  __syncthreads();
#pragma unroll
  for (int i = 0; i < 4; ++i)
    out[(size_t)(n0 + tr + i * 8) * K + (k0 + tc)] = f2bf(tile[tc][tr + i * 8]);
}

__global__ __launch_bounds__(256) void prep_kernel(
    const float* __restrict__ x, const float* __restrict__ p,
    const float* __restrict__ Wq, const float* __restrict__ Ww,
    const float* __restrict__ Wk, const float* __restrict__ Wv,
    u16* __restrict__ x_bf, u16* __restrict__ p_bf,
    u16* __restrict__ wq_t, u16* __restrict__ ww_t, u16* __restrict__ wkv_t) {
  __shared__ float tile[32][33];
  const int bid = blockIdx.x;
  if (bid < 32768) {
    const size_t i = (size_t)bid * 256 + threadIdx.x;
    const float4 a  = ((const float4*)x)[i * 2];
    const float4 b2 = ((const float4*)x)[i * 2 + 1];
    uint4 o;
    o.x = (u32)f2bf(a.x)  | ((u32)f2bf(a.y)  << 16);
    o.y = (u32)f2bf(a.z)  | ((u32)f2bf(a.w)  << 16);
    o.z = (u32)f2bf(b2.x) | ((u32)f2bf(b2.y) << 16);
    o.w = (u32)f2bf(b2.z) | ((u32)f2bf(b2.w) << 16);
    ((uint4*)x_bf)[i] = o;
  } else if (bid < 33076) {
    const int i = (bid - 32768) * 256 + threadIdx.x;
    if (i < 78848) {
      const float4 a  = ((const float4*)p)[(size_t)i * 2];
      const float4 b2 = ((const float4*)p)[(size_t)i * 2 + 1];
      uint4 o;
      o.x = (u32)f2bf(a.x)  | ((u32)f2bf(a.y)  << 16);
      o.y = (u32)f2bf(a.z)  | ((u32)f2bf(a.w)  << 16);
      o.z = (u32)f2bf(b2.x) | ((u32)f2bf(b2.y) << 16);
      o.w = (u32)f2bf(b2.z) | ((u32)f2bf(b2.w) << 16);
      ((uint4*)p_bf)[(size_t)i] = o;
    }
  } else if (bid < 35124) {
    const bool isQ = bid < 34100;
    const int r = (bid - (isQ ? 33076 : 34100));
    transpose_body(isQ ? Wq : Ww, isQ ? wq_t : ww_t, 1024, 1024,
                   (r & 31) * 32, (r >> 5) * 32, tile);
  } else {
    const bool isK = bid < 35636;
    const int r = (bid - (isK ? 35124 : 35636));
    transpose_body(isK ? Wk : Wv, isK ? wkv_t : (wkv_t + 1024 * 512), 512, 1024,
                   (r & 15) * 32, (r >> 4) * 32, tile);
  }
}

// ---------------- small GEMM (128^2, 2-phase dbuf): merged K/V projection ------------
template <bool OUT_BF16>
__global__ __launch_bounds__(256) void gemm_bt(
    const u16* __restrict__ A, const u16* __restrict__ Bt,
    const float* __restrict__ biasA, const float* __restrict__ biasB,
    void* __restrict__ Cout,
    int M, int N, int K, int Mtiles, int Ntiles) {
  __shared__ char Al[2][128 * 32 * 2];
  __shared__ char Bl[2][128 * 32 * 2];

  const int nwg = Mtiles * Ntiles;
  int bid = (int)blockIdx.x;
  bid = (bid & 7) * (nwg >> 3) + (bid >> 3);
  const int mt = bid / Ntiles, nt = bid % Ntiles;
  const int m0 = mt * 128, n0 = nt * 128;

  const int tid = (int)threadIdx.x;
  const int lane = tid & 63;
  const int wv = tid >> 6;
  const int wm = wv & 1, wn = wv >> 1;
  const int lr = lane & 15, lg = lane >> 4;
  const int rsub = lane >> 2;
  const int slot = lane & 3;
  const int rb0 = n0 + rsub;

  auto stage = [&](int buf, int t) {
    const int k0 = t << 5;
#pragma unroll
    for (int c = 0; c < 2; ++c) {
      const int ci = c * 4 + wv;
      int rra = m0 + ci * 16 + rsub;
      if (rra >= M) rra = M - 1;
      gload_lds16(A + (size_t)rra * K + k0 + slot * 8, Al[buf] + ci * 1024);
      const int rrb = rb0 + ci * 16;
      gload_lds16(Bt + (size_t)rrb * K + k0 + slot * 8, Bl[buf] + ci * 1024);
    }
  };

  f32x4 zero4 = {0.f, 0.f, 0.f, 0.f};
  f32x4 acc[4][4];
#pragma unroll
  for (int i = 0; i < 4; ++i)
#pragma unroll
    for (int j = 0; j < 4; ++j) acc[i][j] = zero4;

  const int nk = K >> 5;
  int cur = 0;
  stage(0, 0);
  __syncthreads();

  for (int t = 0; t < nk; ++t) {
    if (t + 1 < nk) stage(cur ^ 1, t + 1);
    frag_t af[4], bf[4];
#pragma unroll
    for (int i = 0; i < 4; ++i) {
      af[i] = *(const frag_t*)(Al[cur] + (wm * 64 + i * 16 + lr) * 64 + lg * 16);
      bf[i] = *(const frag_t*)(Bl[cur] + (wn * 64 + i * 16 + lr) * 64 + lg * 16);
    }
#pragma unroll
    for (int i = 0; i < 4; ++i)
#pragma unroll
      for (int j = 0; j < 4; ++j)
        acc[i][j] = mfma_bf16(af[i], bf[j], acc[i][j]);
    __syncthreads();
    cur ^= 1;
  }

#pragma unroll
  for (int j = 0; j < 4; ++j) {
    const int col = n0 + wn * 64 + j * 16 + lr;
    const float bv = (col < 1024) ? biasA[col] : biasB[col - 1024];
#pragma unroll
    for (int i = 0; i < 4; ++i) {
      const int rbase = m0 + wm * 64 + i * 16 + lg * 4;
#pragma unroll
      for (int r = 0; r < 4; ++r) {
        const int row = rbase + r;
        const float val = acc[i][j][r] + bv;
        if constexpr (OUT_BF16) {
          u32 me = f2bf(val);
          u32 other = __shfl_xor(me, 1);
          if ((lane & 1) == 0 && row < M) {
            *(u32*)((u16*)Cout + (size_t)row * N + col) = me | (other << 16);
          }
        } else {
          if (row < M) ((float*)Cout)[(size_t)row * N + col] = val;
        }
      }
    }
  }
}

// ---------------- m201-faithful 8-phase GEMM: 256^2, BK=64, 8 waves (2Mx4N) ---------
// Derived ledger: A halves = 64-row stripes, half=(r>>6)&1 (Ah0 read P0, Ah1 P2);
// B halves = 32-row stripes, half=(r>>5)&1 (Bh0 read P0, Bh1 P1). Frees: Ah0,Bh0
// after P0; Bh1 after P1; Ah1 after P2. Stage stream (1 half/phase, 3-half lead):
// tau.P0: Ah1(tau+1) -> other buf; P1: Ah0(tau+2); P2: Bh0(tau+2); P3: Bh1(tau+2)
// -> current buf. vmcnt(6) ONLY at P3. Every publish >= 4 phases before its read.
// Verified R15: Q-proj ~197us (vs 233 2-phase), absmax clean.
template <bool OUT_BF16>
__global__ __launch_bounds__(512, 1) void gemm8p(
    const u16* __restrict__ A, const u16* __restrict__ Bt,
    const float* __restrict__ bias, void* __restrict__ Cout,
    int M, int N, int K) {
  __shared__ u16 Al[2][256 * 64];
  __shared__ u16 Bl[2][256 * 64];

  const int Ntiles = N >> 8;
  const int nwg = (M >> 8) * Ntiles;
  int bid = (int)blockIdx.x;
  bid = (bid & 7) * (nwg >> 3) + (bid >> 3);  // bijective: nwg % 8 == 0
  const int mt = bid / Ntiles, ntl = bid % Ntiles;
  const int m0 = mt << 8, n0 = ntl << 8;

  const int tid = (int)threadIdx.x;
  const int lane = tid & 63;
  const int wid = tid >> 6;
  const int wm = wid >> 2, wn = wid & 3;  // 2M x 4N; per-wave out 128x64
  const int lr = lane & 15, lg = lane >> 4;
  const int sslot = (lane & 7) ^ (lane >> 3);
  const int lrow = lane >> 3;

  auto stageA = [&](u16* dst, int half, int t) {
#pragma unroll
    for (int sub = 0; sub < 2; ++sub) {
      const int s = half + sub * 2;
      const u16* g = A + (size_t)(m0 + s * 64 + wid * 8 + lrow) * K + t * 64 + sslot * 8;
      u16* l = dst + (s & 1) * 8192 + (s >> 1) * 4096 + wid * 512;
      gload_lds16(g, l);
    }
  };
  auto stageB = [&](u16* dst, int half, int t) {
#pragma unroll
    for (int sub = 0; sub < 2; ++sub) {
      const int ub = wid * 16 + sub * 8;
      const int r = n0 + (ub >> 5) * 64 + half * 32 + (ub & 31) + lrow;
      const u16* g = Bt + (size_t)r * K + t * 64 + sslot * 8;
      u16* l = dst + half * 8192 + ub * 64;
      gload_lds16(g, l);
    }
  };

  auto ldsA = [&](const u16* base, int r, int ks) -> frag_t {
    const int off = ((r >> 6) & 1) * 8192 + (r >> 7) * 4096 + (r & 63) * 64 +
                    ((((ks) << 2) + lg) ^ (r & 7)) * 8;
    return *(const frag_t*)(base + off);
  };
  auto ldsB = [&](const u16* base, int r, int ks) -> frag_t {
    const int off = ((r >> 5) & 1) * 8192 + (r >> 6) * 2048 + (r & 31) * 64 +
                    ((((ks) << 2) + lg) ^ (r & 7)) * 8;
    return *(const frag_t*)(base + off);
  };

  f32x4 acc[8][4];
#pragma unroll
  for (int i = 0; i < 8; ++i)
#pragma unroll
    for (int j = 0; j < 4; ++j)
#pragma unroll
      for (int r = 0; r < 4; ++r) acc[i][j][r] = 0.f;

  frag_t aR[4][2], b0R[2][2], b1R[2][2];
  auto mmq = [&](frag_t (&bb)[2][2], int mo, int no) {
    __builtin_amdgcn_s_setprio(1);
#pragma unroll
    for (int i = 0; i < 4; ++i)
#pragma unroll
      for (int j = 0; j < 2; ++j) {
        acc[mo + i][no + j] = mfma_bf16(aR[i][0], bb[j][0], acc[mo + i][no + j]);
        acc[mo + i][no + j] = mfma_bf16(aR[i][1], bb[j][1], acc[mo + i][no + j]);
      }
    __builtin_amdgcn_s_setprio(0);
  };

  const int nt = K >> 6;  // >= 3
  const int arow = wm * 128 + lr;
  const int brow = wn * 64 + lr;

  // prologue: tile0 all 4 halves; tile1's Ah0, Bh0, Bh1; vmcnt(6) -> tile0 landed
  stageA(&Al[0][0], 0, 0); stageA(&Al[0][0], 1, 0);
  stageB(&Bl[0][0], 0, 0); stageB(&Bl[0][0], 1, 0);
  stageA(&Al[1][0], 0, 1);
  stageB(&Bl[1][0], 0, 1); stageB(&Bl[1][0], 1, 1);
  asm volatile("s_waitcnt vmcnt(6)" ::: "memory");
  __builtin_amdgcn_s_barrier();

  for (int t = 0; t < nt; ++t) {
    const int cur = t & 1;
    const u16* bA = &Al[cur][0];
    const u16* bB = &Bl[cur][0];
    // ---- P0: read a(mf0-3) + b0 (12 reads); stage Ah1(t+1) -> other buf
#pragma unroll
    for (int i = 0; i < 4; ++i) {
      aR[i][0] = ldsA(bA, arow + i * 16, 0);
      aR[i][1] = ldsA(bA, arow + i * 16, 1);
    }
#pragma unroll
    for (int j = 0; j < 2; ++j) {
      b0R[j][0] = ldsB(bB, brow + j * 16, 0);
      b0R[j][1] = ldsB(bB, brow + j * 16, 1);
    }
    if (t + 1 < nt) stageA(&Al[cur ^ 1][0], 1, t + 1);
    asm volatile("s_waitcnt lgkmcnt(8)" ::: "memory");
    SB0();
    __builtin_amdgcn_s_barrier();
    asm volatile("s_waitcnt lgkmcnt(0)" ::: "memory");
    SB0();
    mmq(b0R, 0, 0);
    __builtin_amdgcn_s_barrier();
    // ---- P1: read b1 (4); stage Ah0(t+2) -> current buf
#pragma unroll
    for (int j = 0; j < 2; ++j) {
      b1R[j][0] = ldsB(bB, brow + 32 + j * 16, 0);
      b1R[j][1] = ldsB(bB, brow + 32 + j * 16, 1);
    }
    if (t + 2 < nt) stageA(&Al[cur][0], 0, t + 2);
    SB0();
    __builtin_amdgcn_s_barrier();
    asm volatile("s_waitcnt lgkmcnt(0)" ::: "memory");
    SB0();
    mmq(b1R, 0, 2);
    __builtin_amdgcn_s_barrier();
    // ---- P2: read a(mf4-7) (8); stage Bh0(t+2)
#pragma unroll
    for (int i = 0; i < 4; ++i) {
      aR[i][0] = ldsA(bA, arow + 64 + i * 16, 0);
      aR[i][1] = ldsA(bA, arow + 64 + i * 16, 1);
    }
    if (t + 2 < nt) stageB(&Bl[cur][0], 0, t + 2);
    SB0();
    __builtin_amdgcn_s_barrier();
    asm volatile("s_waitcnt lgkmcnt(0)" ::: "memory");
    SB0();
    mmq(b1R, 4, 2);
    __builtin_amdgcn_s_barrier();
    // ---- P3: no reads; stage Bh1(t+2); MFMA; counted drain (never 0 mid-loop)
    if (t + 2 < nt) stageB(&Bl[cur][0], 1, t + 2);
    mmq(b0R, 4, 0);
    if (t + 2 < nt)
      asm volatile("s_waitcnt vmcnt(6)" ::: "memory");
    else if (t + 1 < nt)
      asm volatile("s_waitcnt vmcnt(0)" ::: "memory");
    if (t + 1 < nt) __builtin_amdgcn_s_barrier();
  }

  // epilogue: row = m0+wm*128+mf*16+lg*4+rr ; col = n0+wn*64+nf*16+lr
  float bvv[4];
#pragma unroll
  for (int nf = 0; nf < 4; ++nf) bvv[nf] = bias[n0 + wn * 64 + nf * 16 + lr];
#pragma unroll
  for (int mf = 0; mf < 8; ++mf) {
    const int rbase = m0 + wm * 128 + mf * 16 + lg * 4;
#pragma unroll
    for (int rr = 0; rr < 4; ++rr) {
      const int row = rbase + rr;
#pragma unroll
      for (int nf = 0; nf < 4; ++nf) {
        const int cb = n0 + wn * 64 + nf * 16;
        const float val = acc[mf][nf][rr] + bvv[nf];
        if constexpr (OUT_BF16) {
          u32 me = f2bf(val);
          u32 d0 = me | (__shfl_xor(me, 1) << 16);
          u32 d1 = __shfl_xor(d0, 2);
          if ((lane & 3) == 0) {
            uint2 o; o.x = d0; o.y = d1;
            *(uint2*)((u16*)Cout + (size_t)row * N + cb + (lr & 12)) = o;
          }
        } else {
          float v0 = val;
          float v1 = __shfl_xor(v0, 1);
          float v2 = __shfl_xor(v0, 2);
          float v3 = __shfl_xor(v1, 2);
          if ((lane & 3) == 0) {
            float4 o; o.x = v0; o.y = v1; o.z = v2; o.w = v3;
            *(float4*)((float*)Cout + (size_t)row * N + cb + (lr & 12)) = o;
          }
        }
      }
    }
  }
}

// ---------------- attention: 4 q-tiles per block; K/V from merged [1232][2048] ------
__global__ __launch_bounds__(256) void attn_kernel(
    const u16* __restrict__ Q, const u16* __restrict__ KV,
    u16* __restrict__ O) {
  __shared__ u16 Kl[96][72];
  __shared__ u16 Vt[64][104];

  const int bid = blockIdx.x;
  const int qt0 = bid & 15;
  const int h = (bid >> 4) & 15;
  const int b = bid >> 8;
  const int tid = threadIdx.x;

#pragma unroll
  for (int it = 0; it < 3; ++it) {
    const int idx = tid + it * 256;
    const int key = idx >> 3, s = idx & 7;
    uint4 val{0u, 0u, 0u, 0u};
    if (key < 77)
      val = *(const uint4*)(KV + ((size_t)(b * 77 + key)) * 2048 + h * 64 + s * 8);
    *(uint4*)(&Kl[key][s * 8]) = val;
  }
#pragma unroll
  for (int it = 0; it < 3; ++it) {
    const int idx = tid + it * 256;
    if (idx < 616) {
      const int key = idx >> 3, s = idx & 7;
      const uint4 v4 = *(const uint4*)(KV + ((size_t)(b * 77 + key)) * 2048 +
                                       1024 + h * 64 + s * 8);
      const u16* e = (const u16*)&v4;
#pragma unroll
      for (int j = 0; j < 8; ++j) Vt[s * 8 + j][key] = e[j];
    }
  }
#pragma unroll
  for (int it = 0; it < 5; ++it) {
    const int idx = tid + it * 256;
    if (idx < 1216) {
      const int d = idx / 19, kk = 77 + idx % 19;
      Vt[d][kk] = 0;
    }
  }
  __syncthreads();

  const int lane = tid & 63;
  const int wv = tid >> 6;
  const int lr = lane & 15;
  const int lg = lane >> 4;
  f32x4 zero4 = {0.f, 0.f, 0.f, 0.f};

  for (int q4 = 0; q4 < 4; ++q4) {
    const int qt = qt0 * 4 + q4;

    const size_t qrow = (size_t)(b * 4096 + qt * 64 + wv * 16 + lr) * 1024 + h * 64;
    frag_t qf[2];
#pragma unroll
    for (int ks = 0; ks < 2; ++ks)
      qf[ks] = *(const frag_t*)(Q + qrow + ks * 32 + lg * 8);

    f32x4 sa[5] = {zero4, zero4, zero4, zero4, zero4};
#pragma unroll
    for (int ks = 0; ks < 2; ++ks) {
#pragma unroll
      for (int kt = 0; kt < 5; ++kt) {
        frag_t kf = *(const frag_t*)(&Kl[kt * 16 + lr][ks * 32 + lg * 8]);
        sa[kt] = mfma_bf16(kf, qf[ks], sa[kt]);
      }
    }

    float p[5][4];
    float mx = -3.0e38f;
#pragma unroll
    for (int kt = 0; kt < 5; ++kt)
#pragma unroll
      for (int r = 0; r < 4; ++r) {
        const int key = kt * 16 + lg * 4 + r;
        float s = sa[kt][r] * 0.125f;
        if (key >= 77) s = -3.0e38f;
        p[kt][r] = s;
        mx = fmaxf(mx, s);
      }
    mx = fmaxf(mx, __shfl_xor(mx, 16));
    mx = fmaxf(mx, __shfl_xor(mx, 32));
    float sum = 0.f;
#pragma unroll
    for (int kt = 0; kt < 5; ++kt)
#pragma unroll
      for (int r = 0; r < 4; ++r) {
        const float e = __expf(p[kt][r] - mx);
        p[kt][r] = e;
        sum += e;
      }
    sum += __shfl_xor(sum, 16);
    sum += __shfl_xor(sum, 32);
    const float rden = 1.0f / sum;
#pragma unroll
    for (int kt = 0; kt < 5; ++kt)
#pragma unroll
      for (int r = 0; r < 4; ++r) p[kt][r] *= rden;

    union FP { frag_t v; u16 e[8]; };
    frag_t pa[3];
#pragma unroll
    for (int kb = 0; kb < 3; ++kb) {
      FP f;
#pragma unroll
      for (int j = 0; j < 8; ++j) {
        const int kt = 2 * kb + (j >> 2);
        f.e[j] = (kt < 5) ? f2bf(p[kt][j & 3]) : (u16)0;
      }
      pa[kb] = f.v;
    }

    f32x4 oa[4] = {zero4, zero4, zero4, zero4};
#pragma unroll
    for (int nt = 0; nt < 4; ++nt) {
      const int d = nt * 16 + lr;
#pragma unroll
      for (int kb = 0; kb < 3; ++kb) {
        const int key0 = kb * 32 + lg * 4;
        FP vb;
        *(uint2*)(&vb.e[0]) = *(const uint2*)(&Vt[d][key0]);
        *(uint2*)(&vb.e[4]) = *(const uint2*)(&Vt[d][key0 + 16]);
        oa[nt] = mfma_bf16(pa[kb], vb.v, oa[nt]);
      }
    }

#pragma unroll
    for (int nt = 0; nt < 4; ++nt)
#pragma unroll
      for (int r = 0; r < 4; ++r) {
        const int qr = wv * 16 + lg * 4 + r;
        u32 me = f2bf(oa[nt][r]);
        u32 other = __shfl_xor(me, 1);
        if ((lane & 1) == 0) {
          *(u32*)(O + ((size_t)(b * 4096 + qt * 64 + qr)) * 1024 + h * 64 +
                  nt * 16 + lr) = me | (other << 16);
        }
      }
  }
}

// ---------------- launch ----------------
extern "C" void kernel_launch(void* const* d_in, const int* in_sizes, int n_in,
                              void* d_out, int out_size, void* d_ws, size_t ws_size,
                              hipStream_t stream) {
  const float* x  = (const float*)d_in[0];
  const float* p  = (const float*)d_in[1];
  const float* Wq = (const float*)d_in[2];
  const float* bq = (const float*)d_in[3];
  const float* Wk = (const float*)d_in[4];
  const float* bk = (const float*)d_in[5];
  const float* Wv = (const float*)d_in[6];
  const float* bv = (const float*)d_in[7];
  const float* Ww = (const float*)d_in[8];
  const float* bw = (const float*)d_in[9];

  char* ws = (char*)d_ws;
  if (ws_size < 281034752ULL) return;

  u16* x_bf  = (u16*)(ws + 0);          // 65536x1024 bf16; reused as attn_out
  u16* q_bf  = (u16*)(ws + 134217728);  // 65536x1024
  u16* wq_t  = (u16*)(ws + 268435456);  // [1024][1024]
  u16* ww_t  = (u16*)(ws + 270532608);  // [1024][1024]
  u16* wkv_t = (u16*)(ws + 272629760);  // [2048][512]
  u16* p_bf  = (u16*)(ws + 274726912);  // 1232x512
  u16* kv_bf = (u16*)(ws + 275988480);  // [1232][2048]

  prep_kernel<<<36148, 256, 0, stream>>>(x, p, Wq, Ww, Wk, Wv,
                                         x_bf, p_bf, wq_t, ww_t, wkv_t);
  gemm_bt<true><<<160, 256, 0, stream>>>(p_bf, wkv_t, bk, bv, kv_bf,
                                         1232, 2048, 512, 10, 16);
  // Q projection: 8-phase kernel (proven R15)
  gemm8p<true><<<1024, 512, 0, stream>>>(x_bf, wq_t, bq, q_bf, 65536, 1024, 1024);
  attn_kernel<<<4096, 256, 0, stream>>>(q_bf, kv_bf, x_bf);
  // out projection: 8-phase kernel (same shape; fp32 epilogue)
  gemm8p<false><<<1024, 512, 0, stream>>>(x_bf, ww_t, bw, d_out, 65536, 1024, 1024);
}